// Round 4
// baseline (291.818 us; speedup 1.0000x reference)
//
#include <hip/hip_runtime.h>
#include <math.h>

#define BSZ 4
#define SEQ 2048
#define DIM 1024
#define HID 4096
#define MTOT (BSZ * SEQ)   // 8192 tokens
#define NHB 64             // partial h-blocks (32 nt-tiles * 2 wn)
#define EPSF 1e-9f

#define BM 256
#define BN 128
#define BKF 32             // K elems per staging iter
#define KITERS (DIM / BKF) // 32
#define LOSCALE 2048.0f
#define INV_LOSCALE (1.0f / 2048.0f)

typedef _Float16 f16;
typedef _Float16 f16x4 __attribute__((ext_vector_type(4)));
typedef _Float16 f16x8 __attribute__((ext_vector_type(8)));
typedef float f32x16 __attribute__((ext_vector_type(16)));

__device__ __forceinline__ void gl16(const f16* g, f16* l) {
  __builtin_amdgcn_global_load_lds(
      (const __attribute__((address_space(1))) void*)g,
      (__attribute__((address_space(3))) void*)l, 16, 0, 0);
}

// ---------------------------------------------------------------------------
// Split hidden -> fp16 hi/lo (lo scaled by 2048). [8192][1024]
// ---------------------------------------------------------------------------
__global__ void split_a(const float* __restrict__ in, f16* __restrict__ hi,
                        f16* __restrict__ lo) {
  int i = blockIdx.x * 256 + threadIdx.x;   // 4 elems per thread
  float4 v = ((const float4*)in)[i];
  f16x4 h, l;
  h.x = (f16)v.x; h.y = (f16)v.y; h.z = (f16)v.z; h.w = (f16)v.w;
  l.x = (f16)((v.x - (float)h.x) * LOSCALE);
  l.y = (f16)((v.y - (float)h.y) * LOSCALE);
  l.z = (f16)((v.z - (float)h.z) * LOSCALE);
  l.w = (f16)((v.w - (float)h.w) * LOSCALE);
  ((f16x4*)hi)[i] = h;
  ((f16x4*)lo)[i] = l;
}

// ---------------------------------------------------------------------------
// Split + transpose W1 [1024][4096] -> W1T hi/lo fp16 [4096][1024]
// ---------------------------------------------------------------------------
__global__ void split_w1t(const float* __restrict__ w1, f16* __restrict__ hi,
                          f16* __restrict__ lo) {
  __shared__ float tile[32][36];
  const int k0 = blockIdx.x * 32;
  const int h0 = blockIdx.y * 32;
  const int t = threadIdx.x;
  {
    int kk = t >> 3, hq = (t & 7) * 4;
    float4 v = *(const float4*)&w1[(size_t)(k0 + kk) * HID + h0 + hq];
    tile[kk][hq + 0] = v.x; tile[kk][hq + 1] = v.y;
    tile[kk][hq + 2] = v.z; tile[kk][hq + 3] = v.w;
  }
  __syncthreads();
  int hh = t >> 3, kq = (t & 7) * 4;
  f16x4 H, L;
#pragma unroll
  for (int j = 0; j < 4; ++j) {
    float x = tile[kq + j][hh];
    f16 xh = (f16)x;
    H[j] = xh;
    L[j] = (f16)((x - (float)xh) * LOSCALE);
  }
  *(f16x4*)&hi[(size_t)(h0 + hh) * DIM + k0 + kq] = H;
  *(f16x4*)&lo[(size_t)(h0 + hh) * DIM + k0 + kq] = L;
}

// ---------------------------------------------------------------------------
// Gate GEMM v3: 256x128 tile, 8 waves, 3-buffer depth-2 prefetch with counted
// vmcnt(6) (T3+T4), setprio around MFMA (T5), XOR-swizzled LDS (T2, rule 21:
// linear LDS dest + pre-swizzled global source + same involution on reads).
// ---------------------------------------------------------------------------
__global__ __launch_bounds__(512, 2)
void gate_gemm(const f16* __restrict__ Ahi, const f16* __restrict__ Alo,
               const f16* __restrict__ Whi, const f16* __restrict__ Wlo,
               const float* __restrict__ b1, const float* __restrict__ W2,
               float* __restrict__ partial) {
  __shared__ f16 sA[3][BM][64];  // 3 x 32 KB
  __shared__ f16 sB[3][BN][64];  // 3 x 16 KB   total 144 KB

  // XCD-bijective swizzle (1024 % 8 == 0) + 4x4 supertile for L2 reuse
  const int bid = blockIdx.x;
  const int wg = (bid & 7) * 128 + (bid >> 3);
  const int st = wg >> 4, q5 = wg & 15;
  const int mt = (st >> 3) * 4 + (q5 >> 2);  // 0..31
  const int nt = (st & 7) * 4 + (q5 & 3);    // 0..31
  const int m0 = mt * BM, h0 = nt * BN;

  const int t = threadIdx.x;
  const int lane = t & 63, wid = t >> 6;
  const int wm = wid >> 1, wn = wid & 1;     // 4M x 2N wave grid

  f32x16 accM[2][2], accC[2][2];
#pragma unroll
  for (int a = 0; a < 2; ++a)
#pragma unroll
    for (int b = 0; b < 2; ++b)
#pragma unroll
      for (int e = 0; e < 16; ++e) { accM[a][b][e] = 0.f; accC[a][b][e] = 0.f; }

  // staging: A 2048 chunks + B 1024 chunks of 16B; 6 gl_lds per thread.
  // chunk sig -> row r=sig>>3, phys p=sig&7; logical q = p ^ (r&7);
  // q<4 -> hi k-slot q, q>=4 -> lo k-slot q-4. LDS dest linear (wave-uniform
  // base + lane*16 is the gl_lds HW rule).
#define STAGE(buf, kt)                                                        \
  {                                                                           \
    const int k0s = (kt) * BKF;                                               \
    _Pragma("unroll") for (int i = 0; i < 4; ++i) {                           \
      int sig = i * 512 + t;                                                  \
      int r = sig >> 3, p = sig & 7;                                          \
      int q = p ^ (r & 7);                                                    \
      int koff = k0s + (q & 3) * 8;                                           \
      const f16* src = (q < 4) ? (Ahi + (size_t)(m0 + r) * DIM + koff)        \
                               : (Alo + (size_t)(m0 + r) * DIM + koff);       \
      gl16(src, &sA[buf][0][0] + (i * 512 + wid * 64) * 8);                   \
    }                                                                         \
    _Pragma("unroll") for (int i = 0; i < 2; ++i) {                           \
      int sig = i * 512 + t;                                                  \
      int r = sig >> 3, p = sig & 7;                                          \
      int q = p ^ (r & 7);                                                    \
      int koff = k0s + (q & 3) * 8;                                           \
      const f16* src = (q < 4) ? (Whi + (size_t)(h0 + r) * DIM + koff)        \
                               : (Wlo + (size_t)(h0 + r) * DIM + koff);       \
      gl16(src, &sB[buf][0][0] + (i * 512 + wid * 64) * 8);                   \
    }                                                                         \
  }

  // prologue: tiles 0 and 1 in flight; wait tile 0 (12 outstanding -> 6)
  STAGE(0, 0);
  STAGE(1, 1);
  asm volatile("s_waitcnt vmcnt(6)" ::: "memory");
  __builtin_amdgcn_sched_barrier(0);
  __builtin_amdgcn_s_barrier();
  __builtin_amdgcn_sched_barrier(0);

  const int rowl = lane & 31, kb = lane >> 5;

  for (int kt = 0; kt < KITERS; ++kt) {
    const int buf = kt % 3;
    if (kt + 2 < KITERS) STAGE((kt + 2) % 3, kt + 2);

    // 16 ds_read_b128: issue all, then consume per k-slot-group
    f16x8 ah[2][2], al[2][2], bh[2][2], bl[2][2];  // [ks][f]
#pragma unroll
    for (int ks = 0; ks < 2; ++ks) {
      const int sl = ks * 2 + kb;
#pragma unroll
      for (int f = 0; f < 2; ++f) {
        int ra = wm * 64 + f * 32 + rowl;
        int ph = (sl ^ (ra & 7)) * 8;
        ah[ks][f] = *(const f16x8*)&sA[buf][ra][ph];
        al[ks][f] = *(const f16x8*)&sA[buf][ra][ph ^ 32];
        int rb = wn * 64 + f * 32 + rowl;
        int pb = (sl ^ (rb & 7)) * 8;
        bh[ks][f] = *(const f16x8*)&sB[buf][rb][pb];
        bl[ks][f] = *(const f16x8*)&sB[buf][rb][pb ^ 32];
      }
    }

#define MFMA_KS(ks)                                                           \
  _Pragma("unroll") for (int fm = 0; fm < 2; ++fm)                            \
  _Pragma("unroll") for (int fn = 0; fn < 2; ++fn) {                          \
    accM[fm][fn] = __builtin_amdgcn_mfma_f32_32x32x16_f16(                    \
        ah[ks][fm], bh[ks][fn], accM[fm][fn], 0, 0, 0);                       \
    accC[fm][fn] = __builtin_amdgcn_mfma_f32_32x32x16_f16(                    \
        ah[ks][fm], bl[ks][fn], accC[fm][fn], 0, 0, 0);                       \
    accC[fm][fn] = __builtin_amdgcn_mfma_f32_32x32x16_f16(                    \
        al[ks][fm], bh[ks][fn], accC[fm][fn], 0, 0, 0);                       \
  }

    asm volatile("s_waitcnt lgkmcnt(8)" ::: "memory");
    __builtin_amdgcn_sched_barrier(0);
    __builtin_amdgcn_s_setprio(1);
    MFMA_KS(0)
    __builtin_amdgcn_s_setprio(0);
    asm volatile("s_waitcnt lgkmcnt(0)" ::: "memory");
    __builtin_amdgcn_sched_barrier(0);
    __builtin_amdgcn_s_setprio(1);
    MFMA_KS(1)
    __builtin_amdgcn_s_setprio(0);

    // counted drain: steady state keeps next tile's 6 loads in flight
    if (kt < KITERS - 2) {
      asm volatile("s_waitcnt vmcnt(6)" ::: "memory");
    } else {
      asm volatile("s_waitcnt vmcnt(0)" ::: "memory");
    }
    __builtin_amdgcn_sched_barrier(0);
    __builtin_amdgcn_s_barrier();
    __builtin_amdgcn_sched_barrier(0);
  }

  // epilogue: relu(h + b1) * W2, reduce over the 32 h-cols per frag + fn pair
  float b1v[2], w2v[2];
#pragma unroll
  for (int fn = 0; fn < 2; ++fn) {
    int h = h0 + wn * 64 + fn * 32 + rowl;
    b1v[fn] = b1[h];
    w2v[fn] = W2[h];
  }
  float red[2][16];
#pragma unroll
  for (int fm = 0; fm < 2; ++fm)
#pragma unroll
    for (int r = 0; r < 16; ++r) {
      float v0 = accM[fm][0][r] + accC[fm][0][r] * INV_LOSCALE + b1v[0];
      float v1 = accM[fm][1][r] + accC[fm][1][r] * INV_LOSCALE + b1v[1];
      red[fm][r] = fmaxf(v0, 0.f) * w2v[0] + fmaxf(v1, 0.f) * w2v[1];
    }
#pragma unroll
  for (int off = 1; off <= 16; off <<= 1)
#pragma unroll
    for (int fm = 0; fm < 2; ++fm)
#pragma unroll
      for (int r = 0; r < 16; ++r)
        red[fm][r] += __shfl_xor(red[fm][r], off);
  if (rowl == 0) {
    const int hb = nt * 2 + wn;
#pragma unroll
    for (int fm = 0; fm < 2; ++fm)
#pragma unroll
      for (int r = 0; r < 16; ++r) {
        int token = m0 + wm * 64 + fm * 32 + (r & 3) + 8 * (r >> 2) + 4 * kb;
        partial[(size_t)hb * MTOT + token] = red[fm][r];
      }
  }
}

// ---------------------------------------------------------------------------
// Kernel B: logits -> hard boundaries -> scan -> positions/counts/short_mask
// ---------------------------------------------------------------------------
__global__ void boundary_scan(const float* __restrict__ partial,
                              const float* __restrict__ mask,
                              const float* __restrict__ noise,
                              const float* __restrict__ b2,
                              int* __restrict__ bpos, int* __restrict__ counts,
                              int* __restrict__ lengths,
                              float* __restrict__ shortmask) {
  const int b = blockIdx.x;
  const int t = threadIdx.x;
  __shared__ float hardS[SEQ];
  __shared__ float red[256];
  const float bias2 = b2[0];

  float msum = 0.f;
  for (int s = t; s < SEQ; s += 256) {
    float lg = bias2;
#pragma unroll
    for (int h = 0; h < NHB; ++h) lg += partial[(size_t)h * MTOT + b * SEQ + s];
    float u = noise[b * SEQ + s];
    float lgt = logf(u) - log1pf(-u);
    float m = mask[b * SEQ + s];
    float hard = ((lg + lgt) > 0.f) ? 1.f : 0.f;
    hardS[s] = hard * m;
    msum += m;
  }
  red[t] = msum;
  __syncthreads();
  for (int off = 128; off > 0; off >>= 1) {
    if (t < off) red[t] += red[t + off];
    __syncthreads();
  }
  int L = (int)(red[0] + 0.5f);
  __syncthreads();
  if (t == 0) {
    if (L < SEQ) hardS[L - 1] = fmaxf(hardS[L - 1], 1.f);
    lengths[b] = L;
  }
  __syncthreads();

  float loc[8];
  float run = 0.f;
#pragma unroll
  for (int i = 0; i < 8; ++i) { loc[i] = hardS[t * 8 + i]; run += loc[i]; }
  red[t] = run;
  __syncthreads();
  for (int off = 1; off < 256; off <<= 1) {
    float v = (t >= off) ? red[t - off] : 0.f;
    __syncthreads();
    red[t] += v;
    __syncthreads();
  }
  float base = red[t] - run;
  int cnt = (int)(red[255] + 0.5f);

  float pre = base;
#pragma unroll
  for (int i = 0; i < 8; ++i) {
    if (loc[i] > 0.5f) {
      int rank = (int)(pre + 0.5f);
      bpos[b * SEQ + rank] = t * 8 + i;
    }
    pre += loc[i];
  }
  if (t == 0) counts[b] = cnt;
  for (int s = t; s < SEQ; s += 256)
    shortmask[b * SEQ + s] = (s < cnt) ? 1.f : 0.f;
}

// ---------------------------------------------------------------------------
// Pooling kernels (unchanged)
// ---------------------------------------------------------------------------
__global__ void pool_seg(const float* __restrict__ hidden,
                         const int* __restrict__ bpos,
                         const int* __restrict__ counts,
                         float* __restrict__ pooled) {
  const int g = blockIdx.x, b = blockIdx.y;
  const int t = threadIdx.x;
  const int cnt = counts[b];
  float4 acc = {0.f, 0.f, 0.f, 0.f};
  float* outp = pooled + ((size_t)(b * SEQ + g)) * DIM + t * 4;
  if (g > cnt) { *(float4*)outp = acc; return; }
  if (g == cnt) return;
  int start = (g == 0) ? 0 : bpos[b * SEQ + g - 1] + 1;
  int end = bpos[b * SEQ + g] + 1;
  const float* hb = hidden + ((size_t)b * SEQ) * DIM + t * 4;
  for (int l = start; l < end; ++l) {
    float4 v = *(const float4*)(hb + (size_t)l * DIM);
    acc.x += v.x; acc.y += v.y; acc.z += v.z; acc.w += v.w;
  }
  float inv = 1.f / ((float)(end - start) + EPSF);
  acc.x *= inv; acc.y *= inv; acc.z *= inv; acc.w *= inv;
  *(float4*)outp = acc;
}

__global__ void pool_tail_partial(const float* __restrict__ hidden,
                                  const int* __restrict__ bpos,
                                  const int* __restrict__ counts,
                                  float* __restrict__ tailpart) {
  const int c = blockIdx.x;
  const int b = blockIdx.y;
  const int t = threadIdx.x;
  int cnt = counts[b];
  int start = (cnt == 0) ? 0 : bpos[b * SEQ + cnt - 1] + 1;
  int n = SEQ - start;
  int clen = (n + 15) / 16;
  int s0 = start + c * clen;
  int s1 = s0 + clen; if (s1 > SEQ) s1 = SEQ;
  float4 acc = {0.f, 0.f, 0.f, 0.f};
  const float* hb = hidden + ((size_t)b * SEQ) * DIM + t * 4;
  for (int l = s0; l < s1; ++l) {
    float4 v = *(const float4*)(hb + (size_t)l * DIM);
    acc.x += v.x; acc.y += v.y; acc.z += v.z; acc.w += v.w;
  }
  *(float4*)(tailpart + ((size_t)(b * 16 + c)) * DIM + t * 4) = acc;
}

__global__ void pool_tail_final(const int* __restrict__ bpos,
                                const int* __restrict__ counts,
                                const float* __restrict__ tailpart,
                                float* __restrict__ pooled) {
  const int b = blockIdx.x;
  const int t = threadIdx.x;
  int cnt = counts[b];
  if (cnt >= SEQ) return;
  int start = (cnt == 0) ? 0 : bpos[b * SEQ + cnt - 1] + 1;
  float4 acc = {0.f, 0.f, 0.f, 0.f};
  for (int c = 0; c < 16; ++c) {
    float4 v = *(const float4*)(tailpart + ((size_t)(b * 16 + c)) * DIM + t * 4);
    acc.x += v.x; acc.y += v.y; acc.z += v.z; acc.w += v.w;
  }
  float inv = 1.f / ((float)(SEQ - start) + EPSF);
  acc.x *= inv; acc.y *= inv; acc.z *= inv; acc.w *= inv;
  *(float4*)(pooled + ((size_t)(b * SEQ + cnt)) * DIM + t * 4) = acc;
}

__global__ void loss_kernel(const int* __restrict__ counts,
                            const int* __restrict__ lengths,
                            float* __restrict__ outScalars) {
  if (threadIdx.x != 0 || blockIdx.x != 0) return;
  double num_b = 0.0, total = 0.0;
  for (int b = 0; b < BSZ; ++b) { num_b += (double)counts[b]; total += (double)lengths[b]; }
  double lp = lgamma(total + 1.0) - lgamma(num_b + 1.0) - lgamma(total - num_b + 1.0)
            + num_b * log(0.2) + (total - num_b) * log(0.8);
  outScalars[0] = (float)(-lp / total);
  outScalars[1] = (float)num_b;
  outScalars[2] = (float)total;
}

// ---------------------------------------------------------------------------
extern "C" void kernel_launch(void* const* d_in, const int* in_sizes, int n_in,
                              void* d_out, int out_size, void* d_ws, size_t ws_size,
                              hipStream_t stream) {
  const float* hidden = (const float*)d_in[0];
  const float* mask   = (const float*)d_in[1];
  const float* noise  = (const float*)d_in[2];
  const float* W1     = (const float*)d_in[3];
  const float* b1     = (const float*)d_in[4];
  const float* W2     = (const float*)d_in[5];
  const float* b2     = (const float*)d_in[6];

  float* out = (float*)d_out;
  float* pooled = out;
  float* scalars = out + (size_t)BSZ * SEQ * DIM;
  float* shortmask = scalars + 3;

  char* ws = (char*)d_ws;
  size_t off = 0;
  float* partial = (float*)(ws + off); off += (size_t)NHB * MTOT * sizeof(float); // 2 MB
  f16* Ahi = (f16*)(ws + off); off += (size_t)MTOT * DIM * sizeof(f16);           // 16 MB
  f16* Alo = (f16*)(ws + off); off += (size_t)MTOT * DIM * sizeof(f16);           // 16 MB
  f16* Whi = (f16*)(ws + off); off += (size_t)HID * DIM * sizeof(f16);            // 8 MB
  f16* Wlo = (f16*)(ws + off); off += (size_t)HID * DIM * sizeof(f16);            // 8 MB
  int* bpos = (int*)(ws + off); off += (size_t)BSZ * SEQ * sizeof(int);
  int* counts = (int*)(ws + off); off += 16 * sizeof(int);
  int* lengths = (int*)(ws + off); off += 16 * sizeof(int);
  off = (off + 255) & ~(size_t)255;
  float* tailpart = (float*)(ws + off);                                           // 256 KB

  split_a<<<MTOT * DIM / 4 / 256, 256, 0, stream>>>(hidden, Ahi, Alo);
  split_w1t<<<dim3(DIM / 32, HID / 32), 256, 0, stream>>>(W1, Whi, Wlo);
  gate_gemm<<<(MTOT / BM) * (HID / BN), 512, 0, stream>>>(Ahi, Alo, Whi, Wlo,
                                                          b1, W2, partial);
  boundary_scan<<<BSZ, 256, 0, stream>>>(partial, mask, noise, b2,
                                         bpos, counts, lengths, shortmask);
  pool_tail_partial<<<dim3(16, BSZ), 256, 0, stream>>>(hidden, bpos, counts, tailpart);
  pool_seg<<<dim3(SEQ, BSZ), 256, 0, stream>>>(hidden, bpos, counts, pooled);
  pool_tail_final<<<BSZ, 256, 0, stream>>>(bpos, counts, tailpart, pooled);
  loss_kernel<<<1, 1, 0, stream>>>(counts, lengths, scalars);
}

// Round 5
// 271.602 us; speedup vs baseline: 1.0744x; 1.0744x over previous
//
#include <hip/hip_runtime.h>
#include <math.h>

#define BSZ 4
#define SEQ 2048
#define DIM 1024
#define HID 4096
#define MTOT (BSZ * SEQ)   // 8192 tokens
#define NHB 64             // partial h-blocks (16 nt-tiles * 4 wn)
#define EPSF 1e-9f

#define BM 256
#define BN 256
#define BKF 32             // K elems per staging iter
#define KITERS (DIM / BKF) // 32
#define BSCALE 32.0f       // W1 pre-scale: keeps lo-residuals in f16 normal range
#define INV_BSCALE (1.0f / 32.0f)

typedef _Float16 f16;
typedef _Float16 f16x4 __attribute__((ext_vector_type(4)));
typedef _Float16 f16x8 __attribute__((ext_vector_type(8)));
typedef float f32x16 __attribute__((ext_vector_type(16)));

__device__ __forceinline__ void gl16(const f16* g, f16* l) {
  __builtin_amdgcn_global_load_lds(
      (const __attribute__((address_space(1))) void*)g,
      (__attribute__((address_space(3))) void*)l, 16, 0, 0);
}

// ---------------------------------------------------------------------------
// Split hidden -> fp16 hi/lo (lo = exact residual, unscaled). [8192][1024]
// ---------------------------------------------------------------------------
__global__ void split_a(const float* __restrict__ in, f16* __restrict__ hi,
                        f16* __restrict__ lo) {
  int i = blockIdx.x * 256 + threadIdx.x;   // 4 elems per thread
  float4 v = ((const float4*)in)[i];
  f16x4 h, l;
  h.x = (f16)v.x; h.y = (f16)v.y; h.z = (f16)v.z; h.w = (f16)v.w;
  l.x = (f16)(v.x - (float)h.x);
  l.y = (f16)(v.y - (float)h.y);
  l.z = (f16)(v.z - (float)h.z);
  l.w = (f16)(v.w - (float)h.w);
  ((f16x4*)hi)[i] = h;
  ((f16x4*)lo)[i] = l;
}

// ---------------------------------------------------------------------------
// Split + transpose W1 [1024][4096] -> W1T hi/lo fp16 [4096][1024], x32 scale
// (x32 keeps the lo residual of |w|~0.03 entries in f16 NORMAL range)
// ---------------------------------------------------------------------------
__global__ void split_w1t(const float* __restrict__ w1, f16* __restrict__ hi,
                          f16* __restrict__ lo) {
  __shared__ float tile[32][36];
  const int k0 = blockIdx.x * 32;
  const int h0 = blockIdx.y * 32;
  const int t = threadIdx.x;
  {
    int kk = t >> 3, hq = (t & 7) * 4;
    float4 v = *(const float4*)&w1[(size_t)(k0 + kk) * HID + h0 + hq];
    tile[kk][hq + 0] = v.x; tile[kk][hq + 1] = v.y;
    tile[kk][hq + 2] = v.z; tile[kk][hq + 3] = v.w;
  }
  __syncthreads();
  int hh = t >> 3, kq = (t & 7) * 4;
  f16x4 H, L;
#pragma unroll
  for (int j = 0; j < 4; ++j) {
    float x = tile[kq + j][hh] * BSCALE;
    f16 xh = (f16)x;
    H[j] = xh;
    L[j] = (f16)(x - (float)xh);
  }
  *(f16x4*)&hi[(size_t)(h0 + hh) * DIM + k0 + kq] = H;
  *(f16x4*)&lo[(size_t)(h0 + hh) * DIM + k0 + kq] = L;
}

// ---------------------------------------------------------------------------
// Gate GEMM v4: 256x256 tile, 8 waves (2M x 4N), 128x64 wave tile, merged
// single accumulator (3 split-terms into one acc; B pre-scaled x32).
// R3-proven loop structure (stage-early, one __syncthreads per K-tile).
// LDS: XOR-swizzled 128B rows (T2 both-sides, rule 21).
// ---------------------------------------------------------------------------
__global__ __launch_bounds__(512, 2)
void gate_gemm(const f16* __restrict__ Ahi, const f16* __restrict__ Alo,
               const f16* __restrict__ Whi, const f16* __restrict__ Wlo,
               const float* __restrict__ b1, const float* __restrict__ W2,
               float* __restrict__ partial) {
  __shared__ f16 sA[2][BM][64];  // 64 KB
  __shared__ f16 sB[2][BN][64];  // 64 KB

  // XCD swizzle: 512 wg, 64 per XCD; each XCD owns an nt-band of 2 (B-panel
  // 2 MB -> L2-resident) and streams all mt.
  const int bid = blockIdx.x;
  const int wg = (bid & 7) * 64 + (bid >> 3);
  const int nt = wg >> 5;    // 0..15
  const int mt = wg & 31;    // 0..31
  const int m0 = mt * BM, h0 = nt * BN;

  const int t = threadIdx.x;
  const int lane = t & 63, wid = t >> 6;
  const int wm = wid >> 2, wn = wid & 3;   // 2M x 4N wave grid
  const int rowl = lane & 31, kb = lane >> 5;

  f32x16 acc[4][2];
#pragma unroll
  for (int a = 0; a < 4; ++a)
#pragma unroll
    for (int b = 0; b < 2; ++b)
#pragma unroll
      for (int e = 0; e < 16; ++e) acc[a][b][e] = 0.f;

  // Precomputed staging sources (kt-independent): chunk sig -> row r, phys p;
  // logical q = p ^ (r&7); q<4 -> hi k-slot q, q>=4 -> lo k-slot q-4.
  const f16* srcA[4];
  const f16* srcB[4];
#pragma unroll
  for (int i = 0; i < 4; ++i) {
    int sig = i * 512 + t;
    int r = sig >> 3, p = sig & 7;
    int q = p ^ (r & 7);
    int koff = (q & 3) * 8;
    srcA[i] = (q < 4 ? Ahi : Alo) + (size_t)(m0 + r) * DIM + koff;
    srcB[i] = (q < 4 ? Whi : Wlo) + (size_t)(h0 + r) * DIM + koff;
  }

#define STAGE(buf, kt)                                                        \
  {                                                                           \
    _Pragma("unroll") for (int i = 0; i < 4; ++i) {                           \
      int ho = (i * 512 + wid * 64) * 8;                                      \
      gl16(srcA[i] + (size_t)(kt) * BKF, &sA[buf][0][0] + ho);                \
      gl16(srcB[i] + (size_t)(kt) * BKF, &sB[buf][0][0] + ho);                \
    }                                                                         \
  }

  STAGE(0, 0);
  __syncthreads();

  for (int kt = 0; kt < KITERS; ++kt) {
    const int buf = kt & 1;
    if (kt + 1 < KITERS) STAGE(buf ^ 1, kt + 1);
#pragma unroll
    for (int ks = 0; ks < 2; ++ks) {
      f16x8 ah[4], al[4], bh[2], bl[2];
      const int sl = ks * 2 + kb;   // k-slot 0..3
#pragma unroll
      for (int fm = 0; fm < 4; ++fm) {
        int ra = wm * 128 + fm * 32 + rowl;
        int ph = (sl ^ (ra & 7)) * 8;
        ah[fm] = *(const f16x8*)&sA[buf][ra][ph];
        al[fm] = *(const f16x8*)&sA[buf][ra][ph ^ 32];  // lo chunk = hi ^ 4
      }
#pragma unroll
      for (int fn = 0; fn < 2; ++fn) {
        int rb = wn * 64 + fn * 32 + rowl;
        int pb = (sl ^ (rb & 7)) * 8;
        bh[fn] = *(const f16x8*)&sB[buf][rb][pb];
        bl[fn] = *(const f16x8*)&sB[buf][rb][pb ^ 32];
      }
      // term-outermost: dependent same-acc MFMAs are 8 apart (latency-safe)
#pragma unroll
      for (int fm = 0; fm < 4; ++fm)
#pragma unroll
        for (int fn = 0; fn < 2; ++fn)
          acc[fm][fn] = __builtin_amdgcn_mfma_f32_32x32x16_f16(
              ah[fm], bh[fn], acc[fm][fn], 0, 0, 0);
#pragma unroll
      for (int fm = 0; fm < 4; ++fm)
#pragma unroll
        for (int fn = 0; fn < 2; ++fn)
          acc[fm][fn] = __builtin_amdgcn_mfma_f32_32x32x16_f16(
              ah[fm], bl[fn], acc[fm][fn], 0, 0, 0);
#pragma unroll
      for (int fm = 0; fm < 4; ++fm)
#pragma unroll
        for (int fn = 0; fn < 2; ++fn)
          acc[fm][fn] = __builtin_amdgcn_mfma_f32_32x32x16_f16(
              al[fm], bh[fn], acc[fm][fn], 0, 0, 0);
    }
    __syncthreads();
  }

  // epilogue in-place: h = acc/32 + b1; relu*W2; reduce fn then 32 lanes
  float b1v[2], w2v[2];
#pragma unroll
  for (int fn = 0; fn < 2; ++fn) {
    int h = h0 + wn * 64 + fn * 32 + rowl;
    b1v[fn] = b1[h];
    w2v[fn] = W2[h];
  }
#pragma unroll
  for (int fm = 0; fm < 4; ++fm)
#pragma unroll
    for (int r = 0; r < 16; ++r) {
      float v0 = acc[fm][0][r] * INV_BSCALE + b1v[0];
      float v1 = acc[fm][1][r] * INV_BSCALE + b1v[1];
      acc[fm][0][r] = fmaxf(v0, 0.f) * w2v[0] + fmaxf(v1, 0.f) * w2v[1];
    }
#pragma unroll
  for (int off = 1; off <= 16; off <<= 1)
#pragma unroll
    for (int fm = 0; fm < 4; ++fm)
#pragma unroll
      for (int r = 0; r < 16; ++r)
        acc[fm][0][r] += __shfl_xor(acc[fm][0][r], off);
  if (rowl == 0) {
    const int hb = nt * 4 + wn;
#pragma unroll
    for (int fm = 0; fm < 4; ++fm)
#pragma unroll
      for (int r = 0; r < 16; ++r) {
        int token = m0 + wm * 128 + fm * 32 + (r & 3) + 8 * (r >> 2) + 4 * kb;
        partial[(size_t)hb * MTOT + token] = acc[fm][0][r];
      }
  }
}

// ---------------------------------------------------------------------------
// Reduce the 64 partial h-blocks -> logits (parallel, coalesced)
// ---------------------------------------------------------------------------
__global__ void reduce_logits(const float* __restrict__ partial,
                              float* __restrict__ logits) {
  int s = blockIdx.x * 256 + threadIdx.x;
  float lg = 0.f;
#pragma unroll
  for (int h = 0; h < NHB; ++h) lg += partial[(size_t)h * MTOT + s];
  logits[s] = lg;
}

// ---------------------------------------------------------------------------
// Kernel B: logits -> hard boundaries -> scan -> positions/counts/short_mask
// ---------------------------------------------------------------------------
__global__ void boundary_scan(const float* __restrict__ logits,
                              const float* __restrict__ mask,
                              const float* __restrict__ noise,
                              const float* __restrict__ b2,
                              int* __restrict__ bpos, int* __restrict__ counts,
                              int* __restrict__ lengths,
                              float* __restrict__ shortmask) {
  const int b = blockIdx.x;
  const int t = threadIdx.x;
  __shared__ float hardS[SEQ];
  __shared__ float red[256];
  const float bias2 = b2[0];

  float msum = 0.f;
  for (int s = t; s < SEQ; s += 256) {
    float lg = logits[b * SEQ + s] + bias2;
    float u = noise[b * SEQ + s];
    float lgt = logf(u) - log1pf(-u);
    float m = mask[b * SEQ + s];
    float hard = ((lg + lgt) > 0.f) ? 1.f : 0.f;
    hardS[s] = hard * m;
    msum += m;
  }
  red[t] = msum;
  __syncthreads();
  for (int off = 128; off > 0; off >>= 1) {
    if (t < off) red[t] += red[t + off];
    __syncthreads();
  }
  int L = (int)(red[0] + 0.5f);
  __syncthreads();
  if (t == 0) {
    if (L < SEQ) hardS[L - 1] = fmaxf(hardS[L - 1], 1.f);
    lengths[b] = L;
  }
  __syncthreads();

  float loc[8];
  float run = 0.f;
#pragma unroll
  for (int i = 0; i < 8; ++i) { loc[i] = hardS[t * 8 + i]; run += loc[i]; }
  red[t] = run;
  __syncthreads();
  for (int off = 1; off < 256; off <<= 1) {
    float v = (t >= off) ? red[t - off] : 0.f;
    __syncthreads();
    red[t] += v;
    __syncthreads();
  }
  float base = red[t] - run;
  int cnt = (int)(red[255] + 0.5f);

  float pre = base;
#pragma unroll
  for (int i = 0; i < 8; ++i) {
    if (loc[i] > 0.5f) {
      int rank = (int)(pre + 0.5f);
      bpos[b * SEQ + rank] = t * 8 + i;
    }
    pre += loc[i];
  }
  if (t == 0) counts[b] = cnt;
  for (int s = t; s < SEQ; s += 256)
    shortmask[b * SEQ + s] = (s < cnt) ? 1.f : 0.f;
}

// ---------------------------------------------------------------------------
// Pooling kernels (unchanged)
// ---------------------------------------------------------------------------
__global__ void pool_seg(const float* __restrict__ hidden,
                         const int* __restrict__ bpos,
                         const int* __restrict__ counts,
                         float* __restrict__ pooled) {
  const int g = blockIdx.x, b = blockIdx.y;
  const int t = threadIdx.x;
  const int cnt = counts[b];
  float4 acc = {0.f, 0.f, 0.f, 0.f};
  float* outp = pooled + ((size_t)(b * SEQ + g)) * DIM + t * 4;
  if (g > cnt) { *(float4*)outp = acc; return; }
  if (g == cnt) return;
  int start = (g == 0) ? 0 : bpos[b * SEQ + g - 1] + 1;
  int end = bpos[b * SEQ + g] + 1;
  const float* hb = hidden + ((size_t)b * SEQ) * DIM + t * 4;
  for (int l = start; l < end; ++l) {
    float4 v = *(const float4*)(hb + (size_t)l * DIM);
    acc.x += v.x; acc.y += v.y; acc.z += v.z; acc.w += v.w;
  }
  float inv = 1.f / ((float)(end - start) + EPSF);
  acc.x *= inv; acc.y *= inv; acc.z *= inv; acc.w *= inv;
  *(float4*)outp = acc;
}

__global__ void pool_tail_partial(const float* __restrict__ hidden,
                                  const int* __restrict__ bpos,
                                  const int* __restrict__ counts,
                                  float* __restrict__ tailpart) {
  const int c = blockIdx.x;
  const int b = blockIdx.y;
  const int t = threadIdx.x;
  int cnt = counts[b];
  int start = (cnt == 0) ? 0 : bpos[b * SEQ + cnt - 1] + 1;
  int n = SEQ - start;
  int clen = (n + 15) / 16;
  int s0 = start + c * clen;
  int s1 = s0 + clen; if (s1 > SEQ) s1 = SEQ;
  float4 acc = {0.f, 0.f, 0.f, 0.f};
  const float* hb = hidden + ((size_t)b * SEQ) * DIM + t * 4;
  for (int l = s0; l < s1; ++l) {
    float4 v = *(const float4*)(hb + (size_t)l * DIM);
    acc.x += v.x; acc.y += v.y; acc.z += v.z; acc.w += v.w;
  }
  *(float4*)(tailpart + ((size_t)(b * 16 + c)) * DIM + t * 4) = acc;
}

__global__ void pool_tail_final(const int* __restrict__ bpos,
                                const int* __restrict__ counts,
                                const float* __restrict__ tailpart,
                                float* __restrict__ pooled) {
  const int b = blockIdx.x;
  const int t = threadIdx.x;
  int cnt = counts[b];
  if (cnt >= SEQ) return;
  int start = (cnt == 0) ? 0 : bpos[b * SEQ + cnt - 1] + 1;
  float4 acc = {0.f, 0.f, 0.f, 0.f};
  for (int c = 0; c < 16; ++c) {
    float4 v = *(const float4*)(tailpart + ((size_t)(b * 16 + c)) * DIM + t * 4);
    acc.x += v.x; acc.y += v.y; acc.z += v.z; acc.w += v.w;
  }
  float inv = 1.f / ((float)(SEQ - start) + EPSF);
  acc.x *= inv; acc.y *= inv; acc.z *= inv; acc.w *= inv;
  *(float4*)(pooled + ((size_t)(b * SEQ + cnt)) * DIM + t * 4) = acc;
}

__global__ void loss_kernel(const int* __restrict__ counts,
                            const int* __restrict__ lengths,
                            float* __restrict__ outScalars) {
  if (threadIdx.x != 0 || blockIdx.x != 0) return;
  double num_b = 0.0, total = 0.0;
  for (int b = 0; b < BSZ; ++b) { num_b += (double)counts[b]; total += (double)lengths[b]; }
  double lp = lgamma(total + 1.0) - lgamma(num_b + 1.0) - lgamma(total - num_b + 1.0)
            + num_b * log(0.2) + (total - num_b) * log(0.8);
  outScalars[0] = (float)(-lp / total);
  outScalars[1] = (float)num_b;
  outScalars[2] = (float)total;
}

// ---------------------------------------------------------------------------
extern "C" void kernel_launch(void* const* d_in, const int* in_sizes, int n_in,
                              void* d_out, int out_size, void* d_ws, size_t ws_size,
                              hipStream_t stream) {
  const float* hidden = (const float*)d_in[0];
  const float* mask   = (const float*)d_in[1];
  const float* noise  = (const float*)d_in[2];
  const float* W1     = (const float*)d_in[3];
  const float* b1     = (const float*)d_in[4];
  const float* W2     = (const float*)d_in[5];
  const float* b2     = (const float*)d_in[6];

  float* out = (float*)d_out;
  float* pooled = out;
  float* scalars = out + (size_t)BSZ * SEQ * DIM;
  float* shortmask = scalars + 3;

  char* ws = (char*)d_ws;
  size_t off = 0;
  float* partial = (float*)(ws + off); off += (size_t)NHB * MTOT * sizeof(float); // 2 MB
  f16* Ahi = (f16*)(ws + off); off += (size_t)MTOT * DIM * sizeof(f16);           // 16 MB
  f16* Alo = (f16*)(ws + off); off += (size_t)MTOT * DIM * sizeof(f16);           // 16 MB
  f16* Whi = (f16*)(ws + off); off += (size_t)HID * DIM * sizeof(f16);            // 8 MB
  f16* Wlo = (f16*)(ws + off); off += (size_t)HID * DIM * sizeof(f16);            // 8 MB
  float* logits = (float*)(ws + off); off += (size_t)MTOT * sizeof(float);        // 32 KB
  int* bpos = (int*)(ws + off); off += (size_t)BSZ * SEQ * sizeof(int);
  int* counts = (int*)(ws + off); off += 16 * sizeof(int);
  int* lengths = (int*)(ws + off); off += 16 * sizeof(int);
  off = (off + 255) & ~(size_t)255;
  float* tailpart = (float*)(ws + off);                                           // 256 KB

  split_a<<<MTOT * DIM / 4 / 256, 256, 0, stream>>>(hidden, Ahi, Alo);
  split_w1t<<<dim3(DIM / 32, HID / 32), 256, 0, stream>>>(W1, Whi, Wlo);
  gate_gemm<<<(MTOT / BM) * (HID / BN), 512, 0, stream>>>(Ahi, Alo, Whi, Wlo,
                                                          b1, W2, partial);
  reduce_logits<<<MTOT / 256, 256, 0, stream>>>(partial, logits);
  boundary_scan<<<BSZ, 256, 0, stream>>>(logits, mask, noise, b2,
                                         bpos, counts, lengths, shortmask);
  pool_tail_partial<<<dim3(16, BSZ), 256, 0, stream>>>(hidden, bpos, counts, tailpart);
  pool_seg<<<dim3(SEQ, BSZ), 256, 0, stream>>>(hidden, bpos, counts, pooled);
  pool_tail_final<<<BSZ, 256, 0, stream>>>(bpos, counts, tailpart, pooled);
  loss_kernel<<<1, 1, 0, stream>>>(counts, lengths, scalars);
}

// Round 6
// 269.539 us; speedup vs baseline: 1.0827x; 1.0077x over previous
//
#include <hip/hip_runtime.h>
#include <math.h>

#define BSZ 4
#define SEQ 2048
#define DIM 1024
#define HID 4096
#define MTOT (BSZ * SEQ)   // 8192 tokens
#define NHB 64             // partial h-blocks (16 nt-tiles * 4 wn)
#define EPSF 1e-9f

#define BM 256
#define BN 256
#define BKF 32             // K elems per staging iter
#define KITERS (DIM / BKF) // 32
#define BSCALE 32.0f       // W1 pre-scale: keeps lo-residuals in f16 normal range
#define INV_BSCALE (1.0f / 32.0f)

typedef _Float16 f16;
typedef _Float16 f16x4 __attribute__((ext_vector_type(4)));
typedef _Float16 f16x8 __attribute__((ext_vector_type(8)));
typedef float f32x16 __attribute__((ext_vector_type(16)));

__device__ __forceinline__ void gl16(const f16* g, f16* l) {
  __builtin_amdgcn_global_load_lds(
      (const __attribute__((address_space(1))) void*)g,
      (__attribute__((address_space(3))) void*)l, 16, 0, 0);
}

// ---------------------------------------------------------------------------
// Split hidden -> fp16 hi/lo (lo = exact residual). [8192][1024]
// ---------------------------------------------------------------------------
__global__ void split_a(const float* __restrict__ in, f16* __restrict__ hi,
                        f16* __restrict__ lo) {
  int i = blockIdx.x * 256 + threadIdx.x;   // 4 elems per thread
  float4 v = ((const float4*)in)[i];
  f16x4 h, l;
  h.x = (f16)v.x; h.y = (f16)v.y; h.z = (f16)v.z; h.w = (f16)v.w;
  l.x = (f16)(v.x - (float)h.x);
  l.y = (f16)(v.y - (float)h.y);
  l.z = (f16)(v.z - (float)h.z);
  l.w = (f16)(v.w - (float)h.w);
  ((f16x4*)hi)[i] = h;
  ((f16x4*)lo)[i] = l;
}

// ---------------------------------------------------------------------------
// Split + transpose W1 [1024][4096] -> W1T hi/lo fp16 [4096][1024], x32 scale
// ---------------------------------------------------------------------------
__global__ void split_w1t(const float* __restrict__ w1, f16* __restrict__ hi,
                          f16* __restrict__ lo) {
  __shared__ float tile[32][36];
  const int k0 = blockIdx.x * 32;
  const int h0 = blockIdx.y * 32;
  const int t = threadIdx.x;
  {
    int kk = t >> 3, hq = (t & 7) * 4;
    float4 v = *(const float4*)&w1[(size_t)(k0 + kk) * HID + h0 + hq];
    tile[kk][hq + 0] = v.x; tile[kk][hq + 1] = v.y;
    tile[kk][hq + 2] = v.z; tile[kk][hq + 3] = v.w;
  }
  __syncthreads();
  int hh = t >> 3, kq = (t & 7) * 4;
  f16x4 H, L;
#pragma unroll
  for (int j = 0; j < 4; ++j) {
    float x = tile[kq + j][hh] * BSCALE;
    f16 xh = (f16)x;
    H[j] = xh;
    L[j] = (f16)(x - (float)xh);
  }
  *(f16x4*)&hi[(size_t)(h0 + hh) * DIM + k0 + kq] = H;
  *(f16x4*)&lo[(size_t)(h0 + hh) * DIM + k0 + kq] = L;
}

// ---------------------------------------------------------------------------
// Gate GEMM v5: 256x256 tile, 8 waves (2M x 4N), 128x64 wave tile, merged
// accumulator; m201-style 4-phase schedule per K-tile:
//   phase = {ds_read subtile; stage 2 gl_lds; BAR; lgkmcnt(0); setprio(1);
//            12 MFMA; setprio(0); [vmcnt(2) @ p0,p3]; BAR}
// Counted vmcnt derivation: per-tile issue order [B0,B1,B2,B3,A0,A2 | A1,A3]
// (B + A-half1 first, A-half2 last). Before p0 reads (needs B + A-h1): all
// but the 2 newest (A-h2) must be done -> vmcnt(2) at prior p3-end. Before
// p1/p3 reads (need A-h2): vmcnt(2) at p0-end (A-h2 is oldest-2 there).
// Last iteration stages nothing -> vmcnt(0) at its p0-end.
// ---------------------------------------------------------------------------
__global__ __launch_bounds__(512, 2)
void gate_gemm(const f16* __restrict__ Ahi, const f16* __restrict__ Alo,
               const f16* __restrict__ Whi, const f16* __restrict__ Wlo,
               const float* __restrict__ b1, const float* __restrict__ W2,
               float* __restrict__ partial) {
  __shared__ f16 sA[2][BM][64];  // 64 KB
  __shared__ f16 sB[2][BN][64];  // 64 KB

  // XCD swizzle: 512 wg, 64 per XCD; each XCD owns an nt-band of 2 (B-panel
  // L2-resident) and streams all mt.
  const int bid = blockIdx.x;
  const int wg = (bid & 7) * 64 + (bid >> 3);
  const int nt = wg >> 5;    // 0..15
  const int mt = wg & 31;    // 0..31
  const int m0 = mt * BM, h0 = nt * BN;

  const int t = threadIdx.x;
  const int lane = t & 63, wid = t >> 6;
  const int wm = wid >> 2, wn = wid & 3;   // 2M x 4N wave grid
  const int rowl = lane & 31, kb = lane >> 5;
  const int sl0 = kb, sl1 = 2 + kb;

  f32x16 acc[4][2];
#pragma unroll
  for (int a = 0; a < 4; ++a)
#pragma unroll
    for (int b = 0; b < 2; ++b)
#pragma unroll
      for (int e = 0; e < 16; ++e) acc[a][b][e] = 0.f;

  // Precomputed staging sources: chunk sig -> row r = sig>>3, phys p = sig&7;
  // logical q = p ^ (r&7); q<4 -> hi k-slot q, q>=4 -> lo k-slot q-4.
  // Load i covers rows 64i..64i+63: A half1 = loads {0,2}, half2 = {1,3}.
  const f16* srcA[4];
  const f16* srcB[4];
#pragma unroll
  for (int i = 0; i < 4; ++i) {
    int sig = i * 512 + t;
    int r = sig >> 3, p = sig & 7;
    int q = p ^ (r & 7);
    int koff = (q & 3) * 8;
    srcA[i] = (q < 4 ? Ahi : Alo) + (size_t)(m0 + r) * DIM + koff;
    srcB[i] = (q < 4 ? Whi : Wlo) + (size_t)(h0 + r) * DIM + koff;
  }

#define STAGE_B2(buf_, kt_, j)                                                \
  { _Pragma("unroll") for (int i = 2 * (j); i < 2 * (j) + 2; ++i) {           \
      gl16(srcB[i] + (size_t)(kt_) * BKF,                                     \
           &sB[buf_][0][0] + (i * 512 + wid * 64) * 8);                       \
  } }
#define STAGE_A2(buf_, kt_, j)                                                \
  { _Pragma("unroll") for (int ii = 0; ii < 2; ++ii) {                        \
      int i = (j) + ii * 2;                                                   \
      gl16(srcA[i] + (size_t)(kt_) * BKF,                                     \
           &sA[buf_][0][0] + (i * 512 + wid * 64) * 8);                       \
  } }

#define LDA2(fmb, sl)                                                         \
  { _Pragma("unroll") for (int f = 0; f < 2; ++f) {                           \
      int ra = wm * 128 + ((fmb) + f) * 32 + rowl;                            \
      int ph = ((sl) ^ (ra & 7)) * 8;                                         \
      ah[f] = *(const f16x8*)&sA[buf][ra][ph];                                \
      al[f] = *(const f16x8*)&sA[buf][ra][ph ^ 32];                           \
  } }
#define LDB2(sl)                                                              \
  { _Pragma("unroll") for (int n = 0; n < 2; ++n) {                           \
      int rb = wn * 64 + n * 32 + rowl;                                       \
      int pb = ((sl) ^ (rb & 7)) * 8;                                         \
      bh[n] = *(const f16x8*)&sB[buf][rb][pb];                                \
      bl[n] = *(const f16x8*)&sB[buf][rb][pb ^ 32];                           \
  } }

#define MFMA12(fmb)                                                           \
  { _Pragma("unroll") for (int f = 0; f < 2; ++f)                             \
      _Pragma("unroll") for (int n = 0; n < 2; ++n)                           \
        acc[(fmb) + f][n] = __builtin_amdgcn_mfma_f32_32x32x16_f16(           \
            ah[f], bh[n], acc[(fmb) + f][n], 0, 0, 0);                        \
    _Pragma("unroll") for (int f = 0; f < 2; ++f)                             \
      _Pragma("unroll") for (int n = 0; n < 2; ++n)                           \
        acc[(fmb) + f][n] = __builtin_amdgcn_mfma_f32_32x32x16_f16(           \
            ah[f], bl[n], acc[(fmb) + f][n], 0, 0, 0);                        \
    _Pragma("unroll") for (int f = 0; f < 2; ++f)                             \
      _Pragma("unroll") for (int n = 0; n < 2; ++n)                           \
        acc[(fmb) + f][n] = __builtin_amdgcn_mfma_f32_32x32x16_f16(           \
            al[f], bh[n], acc[(fmb) + f][n], 0, 0, 0); }

#define SBAR                                                                  \
  { __builtin_amdgcn_sched_barrier(0); __builtin_amdgcn_s_barrier();          \
    __builtin_amdgcn_sched_barrier(0); }
#define LGKM0                                                                 \
  { asm volatile("s_waitcnt lgkmcnt(0)" ::: "memory");                        \
    __builtin_amdgcn_sched_barrier(0); }

  // prologue: full tile 0 in order [B0..B3, A0, A2, A1, A3]; wait first 6
  STAGE_B2(0, 0, 0); STAGE_B2(0, 0, 1);
  STAGE_A2(0, 0, 0); STAGE_A2(0, 0, 1);
  asm volatile("s_waitcnt vmcnt(2)" ::: "memory");
  SBAR;

  for (int kt = 0; kt < KITERS; ++kt) {
    const int buf = kt & 1;
    const int nbuf = buf ^ 1;
    const bool notlast = (kt + 1 < KITERS);
    f16x8 ah[2], al[2], bh[2], bl[2];

    // -------- phase 0: ks0 x fm01 (A-h1 + all B) --------
    LDA2(0, sl0); LDB2(sl0);
    if (notlast) STAGE_B2(nbuf, kt + 1, 0);
    SBAR;
    LGKM0;
    __builtin_amdgcn_s_setprio(1);
    MFMA12(0);
    __builtin_amdgcn_s_setprio(0);
    __builtin_amdgcn_sched_barrier(0);
    if (notlast) { asm volatile("s_waitcnt vmcnt(2)" ::: "memory"); }
    else         { asm volatile("s_waitcnt vmcnt(0)" ::: "memory"); }
    SBAR;

    // -------- phase 1: ks0 x fm23 (A-h2; b regs reused) --------
    LDA2(2, sl0);
    if (notlast) STAGE_B2(nbuf, kt + 1, 1);
    SBAR;
    LGKM0;
    __builtin_amdgcn_s_setprio(1);
    MFMA12(2);
    __builtin_amdgcn_s_setprio(0);
    SBAR;

    // -------- phase 2: ks1 x fm01 --------
    LDA2(0, sl1); LDB2(sl1);
    if (notlast) STAGE_A2(nbuf, kt + 1, 0);
    SBAR;
    LGKM0;
    __builtin_amdgcn_s_setprio(1);
    MFMA12(0);
    __builtin_amdgcn_s_setprio(0);
    SBAR;

    // -------- phase 3: ks1 x fm23 --------
    LDA2(2, sl1);
    if (notlast) STAGE_A2(nbuf, kt + 1, 1);
    SBAR;
    LGKM0;
    __builtin_amdgcn_s_setprio(1);
    MFMA12(2);
    __builtin_amdgcn_s_setprio(0);
    __builtin_amdgcn_sched_barrier(0);
    if (notlast) { asm volatile("s_waitcnt vmcnt(2)" ::: "memory"); }
    SBAR;
  }

  // epilogue: h = acc/32 + b1; relu*W2; reduce fn then 32 lanes
  float b1v[2], w2v[2];
#pragma unroll
  for (int fn = 0; fn < 2; ++fn) {
    int h = h0 + wn * 64 + fn * 32 + rowl;
    b1v[fn] = b1[h];
    w2v[fn] = W2[h];
  }
#pragma unroll
  for (int fm = 0; fm < 4; ++fm)
#pragma unroll
    for (int r = 0; r < 16; ++r) {
      float v0 = acc[fm][0][r] * INV_BSCALE + b1v[0];
      float v1 = acc[fm][1][r] * INV_BSCALE + b1v[1];
      acc[fm][0][r] = fmaxf(v0, 0.f) * w2v[0] + fmaxf(v1, 0.f) * w2v[1];
    }
#pragma unroll
  for (int off = 1; off <= 16; off <<= 1)
#pragma unroll
    for (int fm = 0; fm < 4; ++fm)
#pragma unroll
      for (int r = 0; r < 16; ++r)
        acc[fm][0][r] += __shfl_xor(acc[fm][0][r], off);
  if (rowl == 0) {
    const int hb = nt * 4 + wn;
#pragma unroll
    for (int fm = 0; fm < 4; ++fm)
#pragma unroll
      for (int r = 0; r < 16; ++r) {
        int token = m0 + wm * 128 + fm * 32 + (r & 3) + 8 * (r >> 2) + 4 * kb;
        partial[(size_t)hb * MTOT + token] = acc[fm][0][r];
      }
  }
}

// ---------------------------------------------------------------------------
// Reduce the 64 partial h-blocks -> logits (parallel, coalesced)
// ---------------------------------------------------------------------------
__global__ void reduce_logits(const float* __restrict__ partial,
                              float* __restrict__ logits) {
  int s = blockIdx.x * 256 + threadIdx.x;
  float lg = 0.f;
#pragma unroll
  for (int h = 0; h < NHB; ++h) lg += partial[(size_t)h * MTOT + s];
  logits[s] = lg;
}

// ---------------------------------------------------------------------------
// Kernel B: logits -> hard boundaries -> scan -> positions/counts/short_mask
// ---------------------------------------------------------------------------
__global__ void boundary_scan(const float* __restrict__ logits,
                              const float* __restrict__ mask,
                              const float* __restrict__ noise,
                              const float* __restrict__ b2,
                              int* __restrict__ bpos, int* __restrict__ counts,
                              int* __restrict__ lengths,
                              float* __restrict__ shortmask) {
  const int b = blockIdx.x;
  const int t = threadIdx.x;
  __shared__ float hardS[SEQ];
  __shared__ float red[256];
  const float bias2 = b2[0];

  float msum = 0.f;
  for (int s = t; s < SEQ; s += 256) {
    float lg = logits[b * SEQ + s] + bias2;
    float u = noise[b * SEQ + s];
    float lgt = logf(u) - log1pf(-u);
    float m = mask[b * SEQ + s];
    float hard = ((lg + lgt) > 0.f) ? 1.f : 0.f;
    hardS[s] = hard * m;
    msum += m;
  }
  red[t] = msum;
  __syncthreads();
  for (int off = 128; off > 0; off >>= 1) {
    if (t < off) red[t] += red[t + off];
    __syncthreads();
  }
  int L = (int)(red[0] + 0.5f);
  __syncthreads();
  if (t == 0) {
    if (L < SEQ) hardS[L - 1] = fmaxf(hardS[L - 1], 1.f);
    lengths[b] = L;
  }
  __syncthreads();

  float loc[8];
  float run = 0.f;
#pragma unroll
  for (int i = 0; i < 8; ++i) { loc[i] = hardS[t * 8 + i]; run += loc[i]; }
  red[t] = run;
  __syncthreads();
  for (int off = 1; off < 256; off <<= 1) {
    float v = (t >= off) ? red[t - off] : 0.f;
    __syncthreads();
    red[t] += v;
    __syncthreads();
  }
  float base = red[t] - run;
  int cnt = (int)(red[255] + 0.5f);

  float pre = base;
#pragma unroll
  for (int i = 0; i < 8; ++i) {
    if (loc[i] > 0.5f) {
      int rank = (int)(pre + 0.5f);
      bpos[b * SEQ + rank] = t * 8 + i;
    }
    pre += loc[i];
  }
  if (t == 0) counts[b] = cnt;
  for (int s = t; s < SEQ; s += 256)
    shortmask[b * SEQ + s] = (s < cnt) ? 1.f : 0.f;
}

// ---------------------------------------------------------------------------
// Pooling kernels (unchanged)
// ---------------------------------------------------------------------------
__global__ void pool_seg(const float* __restrict__ hidden,
                         const int* __restrict__ bpos,
                         const int* __restrict__ counts,
                         float* __restrict__ pooled) {
  const int g = blockIdx.x, b = blockIdx.y;
  const int t = threadIdx.x;
  const int cnt = counts[b];
  float4 acc = {0.f, 0.f, 0.f, 0.f};
  float* outp = pooled + ((size_t)(b * SEQ + g)) * DIM + t * 4;
  if (g > cnt) { *(float4*)outp = acc; return; }
  if (g == cnt) return;
  int start = (g == 0) ? 0 : bpos[b * SEQ + g - 1] + 1;
  int end = bpos[b * SEQ + g] + 1;
  const float* hb = hidden + ((size_t)b * SEQ) * DIM + t * 4;
  for (int l = start; l < end; ++l) {
    float4 v = *(const float4*)(hb + (size_t)l * DIM);
    acc.x += v.x; acc.y += v.y; acc.z += v.z; acc.w += v.w;
  }
  float inv = 1.f / ((float)(end - start) + EPSF);
  acc.x *= inv; acc.y *= inv; acc.z *= inv; acc.w *= inv;
  *(float4*)outp = acc;
}

__global__ void pool_tail_partial(const float* __restrict__ hidden,
                                  const int* __restrict__ bpos,
                                  const int* __restrict__ counts,
                                  float* __restrict__ tailpart) {
  const int c = blockIdx.x;
  const int b = blockIdx.y;
  const int t = threadIdx.x;
  int cnt = counts[b];
  int start = (cnt == 0) ? 0 : bpos[b * SEQ + cnt - 1] + 1;
  int n = SEQ - start;
  int clen = (n + 15) / 16;
  int s0 = start + c * clen;
  int s1 = s0 + clen; if (s1 > SEQ) s1 = SEQ;
  float4 acc = {0.f, 0.f, 0.f, 0.f};
  const float* hb = hidden + ((size_t)b * SEQ) * DIM + t * 4;
  for (int l = s0; l < s1; ++l) {
    float4 v = *(const float4*)(hb + (size_t)l * DIM);
    acc.x += v.x; acc.y += v.y; acc.z += v.z; acc.w += v.w;
  }
  *(float4*)(tailpart + ((size_t)(b * 16 + c)) * DIM + t * 4) = acc;
}

__global__ void pool_tail_final(const int* __restrict__ bpos,
                                const int* __restrict__ counts,
                                const float* __restrict__ tailpart,
                                float* __restrict__ pooled) {
  const int b = blockIdx.x;
  const int t = threadIdx.x;
  int cnt = counts[b];
  if (cnt >= SEQ) return;
  int start = (cnt == 0) ? 0 : bpos[b * SEQ + cnt - 1] + 1;
  float4 acc = {0.f, 0.f, 0.f, 0.f};
  for (int c = 0; c < 16; ++c) {
    float4 v = *(const float4*)(tailpart + ((size_t)(b * 16 + c)) * DIM + t * 4);
    acc.x += v.x; acc.y += v.y; acc.z += v.z; acc.w += v.w;
  }
  float inv = 1.f / ((float)(SEQ - start) + EPSF);
  acc.x *= inv; acc.y *= inv; acc.z *= inv; acc.w *= inv;
  *(float4*)(pooled + ((size_t)(b * SEQ + cnt)) * DIM + t * 4) = acc;
}

__global__ void loss_kernel(const int* __restrict__ counts,
                            const int* __restrict__ lengths,
                            float* __restrict__ outScalars) {
  if (threadIdx.x != 0 || blockIdx.x != 0) return;
  double num_b = 0.0, total = 0.0;
  for (int b = 0; b < BSZ; ++b) { num_b += (double)counts[b]; total += (double)lengths[b]; }
  double lp = lgamma(total + 1.0) - lgamma(num_b + 1.0) - lgamma(total - num_b + 1.0)
            + num_b * log(0.2) + (total - num_b) * log(0.8);
  outScalars[0] = (float)(-lp / total);
  outScalars[1] = (float)num_b;
  outScalars[2] = (float)total;
}

// ---------------------------------------------------------------------------
extern "C" void kernel_launch(void* const* d_in, const int* in_sizes, int n_in,
                              void* d_out, int out_size, void* d_ws, size_t ws_size,
                              hipStream_t stream) {
  const float* hidden = (const float*)d_in[0];
  const float* mask   = (const float*)d_in[1];
  const float* noise  = (const float*)d_in[2];
  const float* W1     = (const float*)d_in[3];
  const float* b1     = (const float*)d_in[4];
  const float* W2     = (const float*)d_in[5];
  const float* b2     = (const float*)d_in[6];

  float* out = (float*)d_out;
  float* pooled = out;
  float* scalars = out + (size_t)BSZ * SEQ * DIM;
  float* shortmask = scalars + 3;

  char* ws = (char*)d_ws;
  size_t off = 0;
  float* partial = (float*)(ws + off); off += (size_t)NHB * MTOT * sizeof(float); // 2 MB
  f16* Ahi = (f16*)(ws + off); off += (size_t)MTOT * DIM * sizeof(f16);           // 16 MB
  f16* Alo = (f16*)(ws + off); off += (size_t)MTOT * DIM * sizeof(f16);           // 16 MB
  f16* Whi = (f16*)(ws + off); off += (size_t)HID * DIM * sizeof(f16);            // 8 MB
  f16* Wlo = (f16*)(ws + off); off += (size_t)HID * DIM * sizeof(f16);            // 8 MB
  float* logits = (float*)(ws + off); off += (size_t)MTOT * sizeof(float);        // 32 KB
  int* bpos = (int*)(ws + off); off += (size_t)BSZ * SEQ * sizeof(int);
  int* counts = (int*)(ws + off); off += 16 * sizeof(int);
  int* lengths = (int*)(ws + off); off += 16 * sizeof(int);
  off = (off + 255) & ~(size_t)255;
  float* tailpart = (float*)(ws + off);                                           // 256 KB

  split_a<<<MTOT * DIM / 4 / 256, 256, 0, stream>>>(hidden, Ahi, Alo);
  split_w1t<<<dim3(DIM / 32, HID / 32), 256, 0, stream>>>(W1, Whi, Wlo);
  gate_gemm<<<(MTOT / BM) * (HID / BN), 512, 0, stream>>>(Ahi, Alo, Whi, Wlo,
                                                          b1, W2, partial);
  reduce_logits<<<MTOT / 256, 256, 0, stream>>>(partial, logits);
  boundary_scan<<<BSZ, 256, 0, stream>>>(logits, mask, noise, b2,
                                         bpos, counts, lengths, shortmask);
  pool_tail_partial<<<dim3(16, BSZ), 256, 0, stream>>>(hidden, bpos, counts, tailpart);
  pool_seg<<<dim3(SEQ, BSZ), 256, 0, stream>>>(hidden, bpos, counts, pooled);
  pool_tail_final<<<BSZ, 256, 0, stream>>>(bpos, counts, tailpart, pooled);
  loss_kernel<<<1, 1, 0, stream>>>(counts, lengths, scalars);
}

// Round 7
// 254.223 us; speedup vs baseline: 1.1479x; 1.0602x over previous
//
#include <hip/hip_runtime.h>
#include <math.h>

#define BSZ 4
#define SEQ 2048
#define DIM 1024
#define HID 4096
#define MTOT (BSZ * SEQ)   // 8192 tokens
#define NHB 64             // partial h-blocks (16 nt-tiles * 4 wn)
#define EPSF 1e-9f

#define BM 256
#define BN 256
#define BKF 32             // K elems per staging iter
#define KITERS (DIM / BKF) // 32
#define BSCALE 32.0f       // W1 pre-scale: keeps lo-residuals in f16 normal range
#define INV_BSCALE (1.0f / 32.0f)

typedef _Float16 f16;
typedef _Float16 f16x4 __attribute__((ext_vector_type(4)));
typedef _Float16 f16x8 __attribute__((ext_vector_type(8)));
typedef float f32x16 __attribute__((ext_vector_type(16)));

__device__ __forceinline__ void gl16(const f16* g, f16* l) {
  __builtin_amdgcn_global_load_lds(
      (const __attribute__((address_space(1))) void*)g,
      (__attribute__((address_space(3))) void*)l, 16, 0, 0);
}

// ---------------------------------------------------------------------------
// Fused split kernel: blocks [0, 8192) split hidden -> f16 hi/lo;
// blocks [8192, 12288) split+transpose W1 (x32 scale) -> W1T hi/lo.
// ---------------------------------------------------------------------------
#define NA_BLOCKS (MTOT * DIM / 4 / 256)   // 8192
#define NW_BLOCKS ((DIM / 32) * (HID / 32)) // 4096

__global__ void split_all(const float* __restrict__ inA, f16* __restrict__ Ahi,
                          f16* __restrict__ Alo, const float* __restrict__ w1,
                          f16* __restrict__ Whi, f16* __restrict__ Wlo) {
  __shared__ float tile[32][36];
  const int bid = blockIdx.x;
  const int t = threadIdx.x;
  if (bid < NA_BLOCKS) {
    int i = bid * 256 + t;   // 4 elems per thread
    float4 v = ((const float4*)inA)[i];
    f16x4 h, l;
    h.x = (f16)v.x; h.y = (f16)v.y; h.z = (f16)v.z; h.w = (f16)v.w;
    l.x = (f16)(v.x - (float)h.x);
    l.y = (f16)(v.y - (float)h.y);
    l.z = (f16)(v.z - (float)h.z);
    l.w = (f16)(v.w - (float)h.w);
    ((f16x4*)Ahi)[i] = h;
    ((f16x4*)Alo)[i] = l;
    return;
  }
  const int wb = bid - NA_BLOCKS;
  const int k0 = (wb & 31) * 32;   // 32 k-tiles
  const int h0 = (wb >> 5) * 32;   // 128 h-tiles
  {
    int kk = t >> 3, hq = (t & 7) * 4;
    float4 v = *(const float4*)&w1[(size_t)(k0 + kk) * HID + h0 + hq];
    tile[kk][hq + 0] = v.x; tile[kk][hq + 1] = v.y;
    tile[kk][hq + 2] = v.z; tile[kk][hq + 3] = v.w;
  }
  __syncthreads();
  int hh = t >> 3, kq = (t & 7) * 4;
  f16x4 H, L;
#pragma unroll
  for (int j = 0; j < 4; ++j) {
    float x = tile[kq + j][hh] * BSCALE;
    f16 xh = (f16)x;
    H[j] = xh;
    L[j] = (f16)(x - (float)xh);
  }
  *(f16x4*)&Whi[(size_t)(h0 + hh) * DIM + k0 + kq] = H;
  *(f16x4*)&Wlo[(size_t)(h0 + hh) * DIM + k0 + kq] = L;
}

// ---------------------------------------------------------------------------
// Gate GEMM v6 (persistent 2-tile): grid 256 = 1 block/CU. Each block computes
// output tiles (mt, nt) and (mt+16, nt) in one continuous 64-kt K-loop; the
// second tile's first stages issue during the first tile's last kt, hiding
// its prologue under the tile-1 epilogue. Same 4-phase counted-vmcnt schedule
// and XOR-swizzled LDS (T2/rule-21) as R6.
// ---------------------------------------------------------------------------
#define A2OFF ((size_t)16 * BM * DIM)   // row offset of second M-tile

__global__ __launch_bounds__(512, 2)
void gate_gemm(const f16* __restrict__ Ahi, const f16* __restrict__ Alo,
               const f16* __restrict__ Whi, const f16* __restrict__ Wlo,
               const float* __restrict__ b1, const float* __restrict__ W2,
               float* __restrict__ partial) {
  __shared__ f16 sA[2][BM][64];  // 64 KB
  __shared__ f16 sB[2][BN][64];  // 64 KB

  // XCD swizzle: 256 wg, 32 per XCD -> 2 nt-bands per XCD (B panels L2-fit)
  const int bid = blockIdx.x;
  const int wg = (bid & 7) * 32 + (bid >> 3);
  const int nt = wg >> 4;    // 0..15
  const int mt = wg & 15;    // 0..15  (tiles mt and mt+16)
  const int m0 = mt * BM, h0 = nt * BN;

  const int t = threadIdx.x;
  const int lane = t & 63, wid = t >> 6;
  const int wm = wid >> 2, wn = wid & 3;   // 2M x 4N wave grid
  const int rowl = lane & 31, kb = lane >> 5;
  const int sl0 = kb, sl1 = 2 + kb;

  f32x16 acc[4][2];
#pragma unroll
  for (int a = 0; a < 4; ++a)
#pragma unroll
    for (int b = 0; b < 2; ++b)
#pragma unroll
      for (int e = 0; e < 16; ++e) acc[a][b][e] = 0.f;

  // staging sources: chunk sig -> row r = sig>>3, phys p = sig&7;
  // logical q = p ^ (r&7); q<4 -> hi k-slot q, q>=4 -> lo k-slot q-4.
  const f16* srcA[4];
  const f16* srcB[4];
#pragma unroll
  for (int i = 0; i < 4; ++i) {
    int sig = i * 512 + t;
    int r = sig >> 3, p = sig & 7;
    int q = p ^ (r & 7);
    int koff = (q & 3) * 8;
    srcA[i] = (q < 4 ? Ahi : Alo) + (size_t)(m0 + r) * DIM + koff;
    srcB[i] = (q < 4 ? Whi : Wlo) + (size_t)(h0 + r) * DIM + koff;
  }

  // kt is the GLOBAL step 0..63; tile = kt>>5; k-offset = (kt&31)*BKF;
  // A source additionally shifts by A2OFF for tile 1 (B panel identical).
#define STAGE_B2(buf_, kt_, j)                                                \
  { _Pragma("unroll") for (int i = 2 * (j); i < 2 * (j) + 2; ++i) {           \
      gl16(srcB[i] + (size_t)((kt_) & 31) * BKF,                              \
           &sB[buf_][0][0] + (i * 512 + wid * 64) * 8);                       \
  } }
#define STAGE_A2(buf_, kt_, j)                                                \
  { _Pragma("unroll") for (int ii = 0; ii < 2; ++ii) {                        \
      int i = (j) + ii * 2;                                                   \
      gl16(srcA[i] + (size_t)((kt_) & 31) * BKF + ((kt_) >> 5) * A2OFF,       \
           &sA[buf_][0][0] + (i * 512 + wid * 64) * 8);                       \
  } }

#define LDA2(fmb, sl)                                                         \
  { _Pragma("unroll") for (int f = 0; f < 2; ++f) {                           \
      int ra = wm * 128 + ((fmb) + f) * 32 + rowl;                            \
      int ph = ((sl) ^ (ra & 7)) * 8;                                         \
      ah[f] = *(const f16x8*)&sA[buf][ra][ph];                                \
      al[f] = *(const f16x8*)&sA[buf][ra][ph ^ 32];                           \
  } }
#define LDB2(sl)                                                              \
  { _Pragma("unroll") for (int n = 0; n < 2; ++n) {                           \
      int rb = wn * 64 + n * 32 + rowl;                                       \
      int pb = ((sl) ^ (rb & 7)) * 8;                                         \
      bh[n] = *(const f16x8*)&sB[buf][rb][pb];                                \
      bl[n] = *(const f16x8*)&sB[buf][rb][pb ^ 32];                           \
  } }

#define MFMA12(fmb)                                                           \
  { _Pragma("unroll") for (int f = 0; f < 2; ++f)                             \
      _Pragma("unroll") for (int n = 0; n < 2; ++n)                           \
        acc[(fmb) + f][n] = __builtin_amdgcn_mfma_f32_32x32x16_f16(           \
            ah[f], bh[n], acc[(fmb) + f][n], 0, 0, 0);                        \
    _Pragma("unroll") for (int f = 0; f < 2; ++f)                             \
      _Pragma("unroll") for (int n = 0; n < 2; ++n)                           \
        acc[(fmb) + f][n] = __builtin_amdgcn_mfma_f32_32x32x16_f16(           \
            ah[f], bl[n], acc[(fmb) + f][n], 0, 0, 0);                        \
    _Pragma("unroll") for (int f = 0; f < 2; ++f)                             \
      _Pragma("unroll") for (int n = 0; n < 2; ++n)                           \
        acc[(fmb) + f][n] = __builtin_amdgcn_mfma_f32_32x32x16_f16(           \
            al[f], bh[n], acc[(fmb) + f][n], 0, 0, 0); }

#define SBAR                                                                  \
  { __builtin_amdgcn_sched_barrier(0); __builtin_amdgcn_s_barrier();          \
    __builtin_amdgcn_sched_barrier(0); }
#define LGKM0                                                                 \
  { asm volatile("s_waitcnt lgkmcnt(0)" ::: "memory");                        \
    __builtin_amdgcn_sched_barrier(0); }

  // epilogue for one finished tile: h = acc/32 + b1; relu*W2; fn-merge;
  // 32-lane shuffle reduce; rowl==0 lanes store. Resets acc afterwards.
#define EPILOG(tile_)                                                         \
  {                                                                           \
    float b1v[2], w2v[2];                                                     \
    _Pragma("unroll") for (int fn = 0; fn < 2; ++fn) {                        \
      int h = h0 + wn * 64 + fn * 32 + rowl;                                  \
      b1v[fn] = b1[h];                                                        \
      w2v[fn] = W2[h];                                                        \
    }                                                                         \
    _Pragma("unroll") for (int fm = 0; fm < 4; ++fm)                          \
      _Pragma("unroll") for (int r = 0; r < 16; ++r) {                        \
        float v0 = acc[fm][0][r] * INV_BSCALE + b1v[0];                       \
        float v1 = acc[fm][1][r] * INV_BSCALE + b1v[1];                       \
        acc[fm][0][r] = fmaxf(v0, 0.f) * w2v[0] + fmaxf(v1, 0.f) * w2v[1];    \
      }                                                                       \
    _Pragma("unroll") for (int off = 1; off <= 16; off <<= 1)                 \
      _Pragma("unroll") for (int fm = 0; fm < 4; ++fm)                        \
        _Pragma("unroll") for (int r = 0; r < 16; ++r)                        \
          acc[fm][0][r] += __shfl_xor(acc[fm][0][r], off);                    \
    if (rowl == 0) {                                                          \
      const int hb = nt * 4 + wn;                                             \
      _Pragma("unroll") for (int fm = 0; fm < 4; ++fm)                        \
        _Pragma("unroll") for (int r = 0; r < 16; ++r) {                      \
          int token = m0 + (tile_) * 4096 + wm * 128 + fm * 32 +              \
                      (r & 3) + 8 * (r >> 2) + 4 * kb;                        \
          partial[(size_t)hb * MTOT + token] = acc[fm][0][r];                 \
        }                                                                     \
    }                                                                         \
    _Pragma("unroll") for (int a = 0; a < 4; ++a)                             \
      _Pragma("unroll") for (int b = 0; b < 2; ++b)                           \
        _Pragma("unroll") for (int e = 0; e < 16; ++e) acc[a][b][e] = 0.f;    \
  }

  // prologue: full step 0 in order [B0..B3, A0, A2, A1, A3]; wait first 6
  STAGE_B2(0, 0, 0); STAGE_B2(0, 0, 1);
  STAGE_A2(0, 0, 0); STAGE_A2(0, 0, 1);
  asm volatile("s_waitcnt vmcnt(2)" ::: "memory");
  SBAR;

#pragma unroll 1
  for (int kt = 0; kt < 2 * KITERS; ++kt) {
    const int buf = kt & 1;
    const int nbuf = buf ^ 1;
    const bool notlast = (kt + 1 < 2 * KITERS);
    f16x8 ah[2], al[2], bh[2], bl[2];

    // -------- phase 0: ks0 x fm01 (A-h1 + all B) --------
    LDA2(0, sl0); LDB2(sl0);
    if (notlast) STAGE_B2(nbuf, kt + 1, 0);
    SBAR;
    LGKM0;
    __builtin_amdgcn_s_setprio(1);
    MFMA12(0);
    __builtin_amdgcn_s_setprio(0);
    __builtin_amdgcn_sched_barrier(0);
    if (notlast) { asm volatile("s_waitcnt vmcnt(2)" ::: "memory"); }
    else         { asm volatile("s_waitcnt vmcnt(0)" ::: "memory"); }
    SBAR;

    // -------- phase 1: ks0 x fm23 (A-h2; b regs reused) --------
    LDA2(2, sl0);
    if (notlast) STAGE_B2(nbuf, kt + 1, 1);
    SBAR;
    LGKM0;
    __builtin_amdgcn_s_setprio(1);
    MFMA12(2);
    __builtin_amdgcn_s_setprio(0);
    SBAR;

    // -------- phase 2: ks1 x fm01 --------
    LDA2(0, sl1); LDB2(sl1);
    if (notlast) STAGE_A2(nbuf, kt + 1, 0);
    SBAR;
    LGKM0;
    __builtin_amdgcn_s_setprio(1);
    MFMA12(0);
    __builtin_amdgcn_s_setprio(0);
    SBAR;

    // -------- phase 3: ks1 x fm23 --------
    LDA2(2, sl1);
    if (notlast) STAGE_A2(nbuf, kt + 1, 1);
    SBAR;
    LGKM0;
    __builtin_amdgcn_s_setprio(1);
    MFMA12(2);
    __builtin_amdgcn_s_setprio(0);
    __builtin_amdgcn_sched_barrier(0);
    if (notlast) { asm volatile("s_waitcnt vmcnt(2)" ::: "memory"); }
    SBAR;

    // tile-1 boundary: emit tile-0 results (tile-1 kt32 stages already in
    // flight from this kt's phases; its p0 reads wait on the vmcnt(2) above)
    if (kt == KITERS - 1) EPILOG(0);
  }
  EPILOG(1);
}

// ---------------------------------------------------------------------------
// Kernel B: fused partial-reduce -> logits -> hard boundaries -> scan ->
// positions/counts/short_mask
// ---------------------------------------------------------------------------
__global__ void boundary_scan(const float* __restrict__ partial,
                              const float* __restrict__ mask,
                              const float* __restrict__ noise,
                              const float* __restrict__ b2,
                              int* __restrict__ bpos, int* __restrict__ counts,
                              int* __restrict__ lengths,
                              float* __restrict__ shortmask) {
  const int b = blockIdx.x;
  const int t = threadIdx.x;
  __shared__ float hardS[SEQ];
  __shared__ float red[256];
  const float bias2 = b2[0];

  float msum = 0.f;
  for (int s = t; s < SEQ; s += 256) {
    float lg = bias2;
#pragma unroll
    for (int h = 0; h < NHB; ++h) lg += partial[(size_t)h * MTOT + b * SEQ + s];
    float u = noise[b * SEQ + s];
    float lgt = logf(u) - log1pf(-u);
    float m = mask[b * SEQ + s];
    float hard = ((lg + lgt) > 0.f) ? 1.f : 0.f;
    hardS[s] = hard * m;
    msum += m;
  }
  red[t] = msum;
  __syncthreads();
  for (int off = 128; off > 0; off >>= 1) {
    if (t < off) red[t] += red[t + off];
    __syncthreads();
  }
  int L = (int)(red[0] + 0.5f);
  __syncthreads();
  if (t == 0) {
    if (L < SEQ) hardS[L - 1] = fmaxf(hardS[L - 1], 1.f);
    lengths[b] = L;
  }
  __syncthreads();

  float loc[8];
  float run = 0.f;
#pragma unroll
  for (int i = 0; i < 8; ++i) { loc[i] = hardS[t * 8 + i]; run += loc[i]; }
  red[t] = run;
  __syncthreads();
  for (int off = 1; off < 256; off <<= 1) {
    float v = (t >= off) ? red[t - off] : 0.f;
    __syncthreads();
    red[t] += v;
    __syncthreads();
  }
  float base = red[t] - run;
  int cnt = (int)(red[255] + 0.5f);

  float pre = base;
#pragma unroll
  for (int i = 0; i < 8; ++i) {
    if (loc[i] > 0.5f) {
      int rank = (int)(pre + 0.5f);
      bpos[b * SEQ + rank] = t * 8 + i;
    }
    pre += loc[i];
  }
  if (t == 0) counts[b] = cnt;
  for (int s = t; s < SEQ; s += 256)
    shortmask[b * SEQ + s] = (s < cnt) ? 1.f : 0.f;
}

// ---------------------------------------------------------------------------
// Pooling kernels (unchanged)
// ---------------------------------------------------------------------------
__global__ void pool_seg(const float* __restrict__ hidden,
                         const int* __restrict__ bpos,
                         const int* __restrict__ counts,
                         float* __restrict__ pooled) {
  const int g = blockIdx.x, b = blockIdx.y;
  const int t = threadIdx.x;
  const int cnt = counts[b];
  float4 acc = {0.f, 0.f, 0.f, 0.f};
  float* outp = pooled + ((size_t)(b * SEQ + g)) * DIM + t * 4;
  if (g > cnt) { *(float4*)outp = acc; return; }
  if (g == cnt) return;
  int start = (g == 0) ? 0 : bpos[b * SEQ + g - 1] + 1;
  int end = bpos[b * SEQ + g] + 1;
  const float* hb = hidden + ((size_t)b * SEQ) * DIM + t * 4;
  for (int l = start; l < end; ++l) {
    float4 v = *(const float4*)(hb + (size_t)l * DIM);
    acc.x += v.x; acc.y += v.y; acc.z += v.z; acc.w += v.w;
  }
  float inv = 1.f / ((float)(end - start) + EPSF);
  acc.x *= inv; acc.y *= inv; acc.z *= inv; acc.w *= inv;
  *(float4*)outp = acc;
}

__global__ void pool_tail_partial(const float* __restrict__ hidden,
                                  const int* __restrict__ bpos,
                                  const int* __restrict__ counts,
                                  float* __restrict__ tailpart) {
  const int c = blockIdx.x;
  const int b = blockIdx.y;
  const int t = threadIdx.x;
  int cnt = counts[b];
  int start = (cnt == 0) ? 0 : bpos[b * SEQ + cnt - 1] + 1;
  int n = SEQ - start;
  int clen = (n + 15) / 16;
  int s0 = start + c * clen;
  int s1 = s0 + clen; if (s1 > SEQ) s1 = SEQ;
  float4 acc = {0.f, 0.f, 0.f, 0.f};
  const float* hb = hidden + ((size_t)b * SEQ) * DIM + t * 4;
  for (int l = s0; l < s1; ++l) {
    float4 v = *(const float4*)(hb + (size_t)l * DIM);
    acc.x += v.x; acc.y += v.y; acc.z += v.z; acc.w += v.w;
  }
  *(float4*)(tailpart + ((size_t)(b * 16 + c)) * DIM + t * 4) = acc;
}

__global__ void pool_tail_final(const int* __restrict__ bpos,
                                const int* __restrict__ counts,
                                const float* __restrict__ tailpart,
                                float* __restrict__ pooled) {
  const int b = blockIdx.x;
  const int t = threadIdx.x;
  int cnt = counts[b];
  if (cnt >= SEQ) return;
  int start = (cnt == 0) ? 0 : bpos[b * SEQ + cnt - 1] + 1;
  float4 acc = {0.f, 0.f, 0.f, 0.f};
  for (int c = 0; c < 16; ++c) {
    float4 v = *(const float4*)(tailpart + ((size_t)(b * 16 + c)) * DIM + t * 4);
    acc.x += v.x; acc.y += v.y; acc.z += v.z; acc.w += v.w;
  }
  float inv = 1.f / ((float)(SEQ - start) + EPSF);
  acc.x *= inv; acc.y *= inv; acc.z *= inv; acc.w *= inv;
  *(float4*)(pooled + ((size_t)(b * SEQ + cnt)) * DIM + t * 4) = acc;
}

__global__ void loss_kernel(const int* __restrict__ counts,
                            const int* __restrict__ lengths,
                            float* __restrict__ outScalars) {
  if (threadIdx.x != 0 || blockIdx.x != 0) return;
  double num_b = 0.0, total = 0.0;
  for (int b = 0; b < BSZ; ++b) { num_b += (double)counts[b]; total += (double)lengths[b]; }
  double lp = lgamma(total + 1.0) - lgamma(num_b + 1.0) - lgamma(total - num_b + 1.0)
            + num_b * log(0.2) + (total - num_b) * log(0.8);
  outScalars[0] = (float)(-lp / total);
  outScalars[1] = (float)num_b;
  outScalars[2] = (float)total;
}

// ---------------------------------------------------------------------------
extern "C" void kernel_launch(void* const* d_in, const int* in_sizes, int n_in,
                              void* d_out, int out_size, void* d_ws, size_t ws_size,
                              hipStream_t stream) {
  const float* hidden = (const float*)d_in[0];
  const float* mask   = (const float*)d_in[1];
  const float* noise  = (const float*)d_in[2];
  const float* W1     = (const float*)d_in[3];
  const float* b1     = (const float*)d_in[4];
  const float* W2     = (const float*)d_in[5];
  const float* b2     = (const float*)d_in[6];

  float* out = (float*)d_out;
  float* pooled = out;
  float* scalars = out + (size_t)BSZ * SEQ * DIM;
  float* shortmask = scalars + 3;

  char* ws = (char*)d_ws;
  size_t off = 0;
  float* partial = (float*)(ws + off); off += (size_t)NHB * MTOT * sizeof(float); // 2 MB
  f16* Ahi = (f16*)(ws + off); off += (size_t)MTOT * DIM * sizeof(f16);           // 16 MB
  f16* Alo = (f16*)(ws + off); off += (size_t)MTOT * DIM * sizeof(f16);           // 16 MB
  f16* Whi = (f16*)(ws + off); off += (size_t)HID * DIM * sizeof(f16);            // 8 MB
  f16* Wlo = (f16*)(ws + off); off += (size_t)HID * DIM * sizeof(f16);            // 8 MB
  int* bpos = (int*)(ws + off); off += (size_t)BSZ * SEQ * sizeof(int);
  int* counts = (int*)(ws + off); off += 16 * sizeof(int);
  int* lengths = (int*)(ws + off); off += 16 * sizeof(int);
  off = (off + 255) & ~(size_t)255;
  float* tailpart = (float*)(ws + off);                                           // 256 KB

  split_all<<<NA_BLOCKS + NW_BLOCKS, 256, 0, stream>>>(hidden, Ahi, Alo,
                                                       W1, Whi, Wlo);
  gate_gemm<<<256, 512, 0, stream>>>(Ahi, Alo, Whi, Wlo, b1, W2, partial);
  boundary_scan<<<BSZ, 256, 0, stream>>>(partial, mask, noise, b2,
                                         bpos, counts, lengths, shortmask);
  pool_tail_partial<<<dim3(16, BSZ), 256, 0, stream>>>(hidden, bpos, counts, tailpart);
  pool_seg<<<dim3(SEQ, BSZ), 256, 0, stream>>>(hidden, bpos, counts, pooled);
  pool_tail_final<<<BSZ, 256, 0, stream>>>(bpos, counts, tailpart, pooled);
  loss_kernel<<<1, 1, 0, stream>>>(counts, lengths, scalars);
}

// Round 8
// 248.393 us; speedup vs baseline: 1.1748x; 1.0235x over previous
//
#include <hip/hip_runtime.h>
#include <math.h>

#define BSZ 4
#define SEQ 2048
#define DIM 1024
#define HID 4096
#define MTOT (BSZ * SEQ)   // 8192 tokens
#define NHB 64             // partial h-blocks (16 nt-tiles * 4 wn)
#define EPSF 1e-9f

#define BM 256
#define BN 256
#define BKF 32             // K elems per staging iter
#define KITERS (DIM / BKF) // 32
#define BSCALE 32.0f       // W1 pre-scale: keeps lo-residuals in f16 normal range
#define INV_BSCALE (1.0f / 32.0f)

typedef _Float16 f16;
typedef _Float16 f16x4 __attribute__((ext_vector_type(4)));
typedef _Float16 f16x8 __attribute__((ext_vector_type(8)));
typedef float f32x16 __attribute__((ext_vector_type(16)));

__device__ __forceinline__ void gl16(const f16* g, f16* l) {
  __builtin_amdgcn_global_load_lds(
      (const __attribute__((address_space(1))) void*)g,
      (__attribute__((address_space(3))) void*)l, 16, 0, 0);
}

// ---------------------------------------------------------------------------
// Fused split kernel: blocks [0, 4096) split hidden -> f16 hi/lo (8 elem/thr,
// 16B stores); blocks [4096, 8192) split+transpose W1 (x32) -> W1T hi/lo.
// ---------------------------------------------------------------------------
#define NA_BLOCKS (MTOT * DIM / 8 / 256)    // 4096
#define NW_BLOCKS ((DIM / 32) * (HID / 32)) // 4096

__global__ void split_all(const float* __restrict__ inA, f16* __restrict__ Ahi,
                          f16* __restrict__ Alo, const float* __restrict__ w1,
                          f16* __restrict__ Whi, f16* __restrict__ Wlo) {
  __shared__ float tile[32][36];
  const int bid = blockIdx.x;
  const int t = threadIdx.x;
  if (bid < NA_BLOCKS) {
    int i = bid * 256 + t;   // 8 elems per thread
    const float4* inp = (const float4*)inA + (size_t)i * 2;
    float4 v0 = inp[0], v1 = inp[1];
    f16x8 h, l;
    h[0] = (f16)v0.x; h[1] = (f16)v0.y; h[2] = (f16)v0.z; h[3] = (f16)v0.w;
    h[4] = (f16)v1.x; h[5] = (f16)v1.y; h[6] = (f16)v1.z; h[7] = (f16)v1.w;
    l[0] = (f16)(v0.x - (float)h[0]); l[1] = (f16)(v0.y - (float)h[1]);
    l[2] = (f16)(v0.z - (float)h[2]); l[3] = (f16)(v0.w - (float)h[3]);
    l[4] = (f16)(v1.x - (float)h[4]); l[5] = (f16)(v1.y - (float)h[5]);
    l[6] = (f16)(v1.z - (float)h[6]); l[7] = (f16)(v1.w - (float)h[7]);
    ((f16x8*)Ahi)[i] = h;
    ((f16x8*)Alo)[i] = l;
    return;
  }
  const int wb = bid - NA_BLOCKS;
  const int k0 = (wb & 31) * 32;   // 32 k-tiles
  const int h0 = (wb >> 5) * 32;   // 128 h-tiles
  {
    int kk = t >> 3, hq = (t & 7) * 4;
    float4 v = *(const float4*)&w1[(size_t)(k0 + kk) * HID + h0 + hq];
    tile[kk][hq + 0] = v.x; tile[kk][hq + 1] = v.y;
    tile[kk][hq + 2] = v.z; tile[kk][hq + 3] = v.w;
  }
  __syncthreads();
  int hh = t >> 3, kq = (t & 7) * 4;
  f16x4 H, L;
#pragma unroll
  for (int j = 0; j < 4; ++j) {
    float x = tile[kq + j][hh] * BSCALE;
    f16 xh = (f16)x;
    H[j] = xh;
    L[j] = (f16)(x - (float)xh);
  }
  *(f16x4*)&Whi[(size_t)(h0 + hh) * DIM + k0 + kq] = H;
  *(f16x4*)&Wlo[(size_t)(h0 + hh) * DIM + k0 + kq] = L;
}

// ---------------------------------------------------------------------------
// Gate GEMM (persistent 2-tile, R7-proven): grid 256 = 1 block/CU. Each block
// computes tiles (mt, nt) and (mt+16, nt) in one 64-kt K-loop. 4-phase
// counted-vmcnt schedule, XOR-swizzled LDS (T2/rule-21).
// ---------------------------------------------------------------------------
#define A2OFF ((size_t)16 * BM * DIM)   // row offset of second M-tile

__global__ __launch_bounds__(512, 2)
void gate_gemm(const f16* __restrict__ Ahi, const f16* __restrict__ Alo,
               const f16* __restrict__ Whi, const f16* __restrict__ Wlo,
               const float* __restrict__ b1, const float* __restrict__ W2,
               float* __restrict__ partial) {
  __shared__ f16 sA[2][BM][64];  // 64 KB
  __shared__ f16 sB[2][BN][64];  // 64 KB

  const int bid = blockIdx.x;
  const int wg = (bid & 7) * 32 + (bid >> 3);
  const int nt = wg >> 4;    // 0..15
  const int mt = wg & 15;    // 0..15  (tiles mt and mt+16)
  const int m0 = mt * BM, h0 = nt * BN;

  const int t = threadIdx.x;
  const int lane = t & 63, wid = t >> 6;
  const int wm = wid >> 2, wn = wid & 3;   // 2M x 4N wave grid
  const int rowl = lane & 31, kb = lane >> 5;
  const int sl0 = kb, sl1 = 2 + kb;

  f32x16 acc[4][2];
#pragma unroll
  for (int a = 0; a < 4; ++a)
#pragma unroll
    for (int b = 0; b < 2; ++b)
#pragma unroll
      for (int e = 0; e < 16; ++e) acc[a][b][e] = 0.f;

  const f16* srcA[4];
  const f16* srcB[4];
#pragma unroll
  for (int i = 0; i < 4; ++i) {
    int sig = i * 512 + t;
    int r = sig >> 3, p = sig & 7;
    int q = p ^ (r & 7);
    int koff = (q & 3) * 8;
    srcA[i] = (q < 4 ? Ahi : Alo) + (size_t)(m0 + r) * DIM + koff;
    srcB[i] = (q < 4 ? Whi : Wlo) + (size_t)(h0 + r) * DIM + koff;
  }

#define STAGE_B2(buf_, kt_, j)                                                \
  { _Pragma("unroll") for (int i = 2 * (j); i < 2 * (j) + 2; ++i) {           \
      gl16(srcB[i] + (size_t)((kt_) & 31) * BKF,                              \
           &sB[buf_][0][0] + (i * 512 + wid * 64) * 8);                       \
  } }
#define STAGE_A2(buf_, kt_, j)                                                \
  { _Pragma("unroll") for (int ii = 0; ii < 2; ++ii) {                        \
      int i = (j) + ii * 2;                                                   \
      gl16(srcA[i] + (size_t)((kt_) & 31) * BKF + ((kt_) >> 5) * A2OFF,       \
           &sA[buf_][0][0] + (i * 512 + wid * 64) * 8);                       \
  } }

#define LDA2(fmb, sl)                                                         \
  { _Pragma("unroll") for (int f = 0; f < 2; ++f) {                           \
      int ra = wm * 128 + ((fmb) + f) * 32 + rowl;                            \
      int ph = ((sl) ^ (ra & 7)) * 8;                                         \
      ah[f] = *(const f16x8*)&sA[buf][ra][ph];                                \
      al[f] = *(const f16x8*)&sA[buf][ra][ph ^ 32];                           \
  } }
#define LDB2(sl)                                                              \
  { _Pragma("unroll") for (int n = 0; n < 2; ++n) {                           \
      int rb = wn * 64 + n * 32 + rowl;                                       \
      int pb = ((sl) ^ (rb & 7)) * 8;                                         \
      bh[n] = *(const f16x8*)&sB[buf][rb][pb];                                \
      bl[n] = *(const f16x8*)&sB[buf][rb][pb ^ 32];                           \
  } }

#define MFMA12(fmb)                                                           \
  { _Pragma("unroll") for (int f = 0; f < 2; ++f)                             \
      _Pragma("unroll") for (int n = 0; n < 2; ++n)                           \
        acc[(fmb) + f][n] = __builtin_amdgcn_mfma_f32_32x32x16_f16(           \
            ah[f], bh[n], acc[(fmb) + f][n], 0, 0, 0);                        \
    _Pragma("unroll") for (int f = 0; f < 2; ++f)                             \
      _Pragma("unroll") for (int n = 0; n < 2; ++n)                           \
        acc[(fmb) + f][n] = __builtin_amdgcn_mfma_f32_32x32x16_f16(           \
            ah[f], bl[n], acc[(fmb) + f][n], 0, 0, 0);                        \
    _Pragma("unroll") for (int f = 0; f < 2; ++f)                             \
      _Pragma("unroll") for (int n = 0; n < 2; ++n)                           \
        acc[(fmb) + f][n] = __builtin_amdgcn_mfma_f32_32x32x16_f16(           \
            al[f], bh[n], acc[(fmb) + f][n], 0, 0, 0); }

#define SBAR                                                                  \
  { __builtin_amdgcn_sched_barrier(0); __builtin_amdgcn_s_barrier();          \
    __builtin_amdgcn_sched_barrier(0); }
#define LGKM0                                                                 \
  { asm volatile("s_waitcnt lgkmcnt(0)" ::: "memory");                        \
    __builtin_amdgcn_sched_barrier(0); }

#define EPILOG(tile_)                                                         \
  {                                                                           \
    float b1v[2], w2v[2];                                                     \
    _Pragma("unroll") for (int fn = 0; fn < 2; ++fn) {                        \
      int h = h0 + wn * 64 + fn * 32 + rowl;                                  \
      b1v[fn] = b1[h];                                                        \
      w2v[fn] = W2[h];                                                        \
    }                                                                         \
    _Pragma("unroll") for (int fm = 0; fm < 4; ++fm)                          \
      _Pragma("unroll") for (int r = 0; r < 16; ++r) {                        \
        float v0 = acc[fm][0][r] * INV_BSCALE + b1v[0];                       \
        float v1 = acc[fm][1][r] * INV_BSCALE + b1v[1];                       \
        acc[fm][0][r] = fmaxf(v0, 0.f) * w2v[0] + fmaxf(v1, 0.f) * w2v[1];    \
      }                                                                       \
    _Pragma("unroll") for (int off = 1; off <= 16; off <<= 1)                 \
      _Pragma("unroll") for (int fm = 0; fm < 4; ++fm)                        \
        _Pragma("unroll") for (int r = 0; r < 16; ++r)                        \
          acc[fm][0][r] += __shfl_xor(acc[fm][0][r], off);                    \
    if (rowl == 0) {                                                          \
      const int hb = nt * 4 + wn;                                             \
      _Pragma("unroll") for (int fm = 0; fm < 4; ++fm)                        \
        _Pragma("unroll") for (int r = 0; r < 16; ++r) {                      \
          int token = m0 + (tile_) * 4096 + wm * 128 + fm * 32 +              \
                      (r & 3) + 8 * (r >> 2) + 4 * kb;                        \
          partial[(size_t)hb * MTOT + token] = acc[fm][0][r];                 \
        }                                                                     \
    }                                                                         \
    _Pragma("unroll") for (int a = 0; a < 4; ++a)                             \
      _Pragma("unroll") for (int b = 0; b < 2; ++b)                           \
        _Pragma("unroll") for (int e = 0; e < 16; ++e) acc[a][b][e] = 0.f;    \
  }

  STAGE_B2(0, 0, 0); STAGE_B2(0, 0, 1);
  STAGE_A2(0, 0, 0); STAGE_A2(0, 0, 1);
  asm volatile("s_waitcnt vmcnt(2)" ::: "memory");
  SBAR;

#pragma unroll 1
  for (int kt = 0; kt < 2 * KITERS; ++kt) {
    const int buf = kt & 1;
    const int nbuf = buf ^ 1;
    const bool notlast = (kt + 1 < 2 * KITERS);
    f16x8 ah[2], al[2], bh[2], bl[2];

    // phase 0: ks0 x fm01
    LDA2(0, sl0); LDB2(sl0);
    if (notlast) STAGE_B2(nbuf, kt + 1, 0);
    SBAR;
    LGKM0;
    __builtin_amdgcn_s_setprio(1);
    MFMA12(0);
    __builtin_amdgcn_s_setprio(0);
    __builtin_amdgcn_sched_barrier(0);
    if (notlast) { asm volatile("s_waitcnt vmcnt(2)" ::: "memory"); }
    else         { asm volatile("s_waitcnt vmcnt(0)" ::: "memory"); }
    SBAR;

    // phase 1: ks0 x fm23
    LDA2(2, sl0);
    if (notlast) STAGE_B2(nbuf, kt + 1, 1);
    SBAR;
    LGKM0;
    __builtin_amdgcn_s_setprio(1);
    MFMA12(2);
    __builtin_amdgcn_s_setprio(0);
    SBAR;

    // phase 2: ks1 x fm01
    LDA2(0, sl1); LDB2(sl1);
    if (notlast) STAGE_A2(nbuf, kt + 1, 0);
    SBAR;
    LGKM0;
    __builtin_amdgcn_s_setprio(1);
    MFMA12(0);
    __builtin_amdgcn_s_setprio(0);
    SBAR;

    // phase 3: ks1 x fm23
    LDA2(2, sl1);
    if (notlast) STAGE_A2(nbuf, kt + 1, 1);
    SBAR;
    LGKM0;
    __builtin_amdgcn_s_setprio(1);
    MFMA12(2);
    __builtin_amdgcn_s_setprio(0);
    __builtin_amdgcn_sched_barrier(0);
    if (notlast) { asm volatile("s_waitcnt vmcnt(2)" ::: "memory"); }
    SBAR;

    if (kt == KITERS - 1) EPILOG(0);
  }
  EPILOG(1);
}

// ---------------------------------------------------------------------------
// Kernel B: fused partial-reduce -> logits -> hard boundaries -> scan ->
// positions/counts/short_mask
// ---------------------------------------------------------------------------
__global__ void boundary_scan(const float* __restrict__ partial,
                              const float* __restrict__ mask,
                              const float* __restrict__ noise,
                              const float* __restrict__ b2,
                              int* __restrict__ bpos, int* __restrict__ counts,
                              int* __restrict__ lengths,
                              float* __restrict__ shortmask) {
  const int b = blockIdx.x;
  const int t = threadIdx.x;
  __shared__ float hardS[SEQ];
  __shared__ float red[256];
  const float bias2 = b2[0];

  float msum = 0.f;
  for (int s = t; s < SEQ; s += 256) {
    float lg = bias2;
#pragma unroll
    for (int h = 0; h < NHB; ++h) lg += partial[(size_t)h * MTOT + b * SEQ + s];
    float u = noise[b * SEQ + s];
    float lgt = logf(u) - log1pf(-u);
    float m = mask[b * SEQ + s];
    float hard = ((lg + lgt) > 0.f) ? 1.f : 0.f;
    hardS[s] = hard * m;
    msum += m;
  }
  red[t] = msum;
  __syncthreads();
  for (int off = 128; off > 0; off >>= 1) {
    if (t < off) red[t] += red[t + off];
    __syncthreads();
  }
  int L = (int)(red[0] + 0.5f);
  __syncthreads();
  if (t == 0) {
    if (L < SEQ) hardS[L - 1] = fmaxf(hardS[L - 1], 1.f);
    lengths[b] = L;
  }
  __syncthreads();

  float loc[8];
  float run = 0.f;
#pragma unroll
  for (int i = 0; i < 8; ++i) { loc[i] = hardS[t * 8 + i]; run += loc[i]; }
  red[t] = run;
  __syncthreads();
  for (int off = 1; off < 256; off <<= 1) {
    float v = (t >= off) ? red[t - off] : 0.f;
    __syncthreads();
    red[t] += v;
    __syncthreads();
  }
  float base = red[t] - run;
  int cnt = (int)(red[255] + 0.5f);

  float pre = base;
#pragma unroll
  for (int i = 0; i < 8; ++i) {
    if (loc[i] > 0.5f) {
      int rank = (int)(pre + 0.5f);
      bpos[b * SEQ + rank] = t * 8 + i;
    }
    pre += loc[i];
  }
  if (t == 0) counts[b] = cnt;
  for (int s = t; s < SEQ; s += 256)
    shortmask[b * SEQ + s] = (s < cnt) ? 1.f : 0.f;
}

// ---------------------------------------------------------------------------
// Tail partial sums (16 chunks per row) + fused loss (block (0,0), thread 0)
// ---------------------------------------------------------------------------
__global__ void pool_tail_partial(const float* __restrict__ hidden,
                                  const int* __restrict__ bpos,
                                  const int* __restrict__ counts,
                                  const int* __restrict__ lengths,
                                  float* __restrict__ tailpart,
                                  float* __restrict__ outScalars) {
  const int c = blockIdx.x;
  const int b = blockIdx.y;
  const int t = threadIdx.x;
  int cnt = counts[b];
  int start = (cnt == 0) ? 0 : bpos[b * SEQ + cnt - 1] + 1;
  int n = SEQ - start;
  int clen = (n + 15) / 16;
  int s0 = start + c * clen;
  int s1 = s0 + clen; if (s1 > SEQ) s1 = SEQ;
  float4 acc = {0.f, 0.f, 0.f, 0.f};
  const float* hb = hidden + ((size_t)b * SEQ) * DIM + t * 4;
  for (int l = s0; l < s1; ++l) {
    float4 v = *(const float4*)(hb + (size_t)l * DIM);
    acc.x += v.x; acc.y += v.y; acc.z += v.z; acc.w += v.w;
  }
  *(float4*)(tailpart + ((size_t)(b * 16 + c)) * DIM + t * 4) = acc;

  if (c == 0 && b == 0 && t == 0) {
    double num_b = 0.0, total = 0.0;
    for (int bb = 0; bb < BSZ; ++bb) {
      num_b += (double)counts[bb];
      total += (double)lengths[bb];
    }
    double lp = lgamma(total + 1.0) - lgamma(num_b + 1.0)
              - lgamma(total - num_b + 1.0)
              + num_b * log(0.2) + (total - num_b) * log(0.8);
    outScalars[0] = (float)(-lp / total);
    outScalars[1] = (float)num_b;
    outScalars[2] = (float)total;
  }
}

// ---------------------------------------------------------------------------
// Segment mean pooling; block g==cnt combines the 16 tail partials (absorbs
// the old pool_tail_final — tailpart was written by the previous dispatch).
// ---------------------------------------------------------------------------
__global__ void pool_seg(const float* __restrict__ hidden,
                         const int* __restrict__ bpos,
                         const int* __restrict__ counts,
                         const float* __restrict__ tailpart,
                         float* __restrict__ pooled) {
  const int g = blockIdx.x, b = blockIdx.y;
  const int t = threadIdx.x;
  const int cnt = counts[b];
  float4 acc = {0.f, 0.f, 0.f, 0.f};
  float* outp = pooled + ((size_t)(b * SEQ + g)) * DIM + t * 4;
  if (g > cnt) { *(float4*)outp = acc; return; }
  if (g == cnt) {
    int start = (cnt == 0) ? 0 : bpos[b * SEQ + cnt - 1] + 1;
    for (int c = 0; c < 16; ++c) {
      float4 v = *(const float4*)(tailpart + ((size_t)(b * 16 + c)) * DIM + t * 4);
      acc.x += v.x; acc.y += v.y; acc.z += v.z; acc.w += v.w;
    }
    float inv = 1.f / ((float)(SEQ - start) + EPSF);
    acc.x *= inv; acc.y *= inv; acc.z *= inv; acc.w *= inv;
    *(float4*)outp = acc;
    return;
  }
  int start = (g == 0) ? 0 : bpos[b * SEQ + g - 1] + 1;
  int end = bpos[b * SEQ + g] + 1;
  const float* hb = hidden + ((size_t)b * SEQ) * DIM + t * 4;
  for (int l = start; l < end; ++l) {
    float4 v = *(const float4*)(hb + (size_t)l * DIM);
    acc.x += v.x; acc.y += v.y; acc.z += v.z; acc.w += v.w;
  }
  float inv = 1.f / ((float)(end - start) + EPSF);
  acc.x *= inv; acc.y *= inv; acc.z *= inv; acc.w *= inv;
  *(float4*)outp = acc;
}

// ---------------------------------------------------------------------------
extern "C" void kernel_launch(void* const* d_in, const int* in_sizes, int n_in,
                              void* d_out, int out_size, void* d_ws, size_t ws_size,
                              hipStream_t stream) {
  const float* hidden = (const float*)d_in[0];
  const float* mask   = (const float*)d_in[1];
  const float* noise  = (const float*)d_in[2];
  const float* W1     = (const float*)d_in[3];
  const float* b1     = (const float*)d_in[4];
  const float* W2     = (const float*)d_in[5];
  const float* b2     = (const float*)d_in[6];

  float* out = (float*)d_out;
  float* pooled = out;
  float* scalars = out + (size_t)BSZ * SEQ * DIM;
  float* shortmask = scalars + 3;

  char* ws = (char*)d_ws;
  size_t off = 0;
  float* partial = (float*)(ws + off); off += (size_t)NHB * MTOT * sizeof(float); // 2 MB
  f16* Ahi = (f16*)(ws + off); off += (size_t)MTOT * DIM * sizeof(f16);           // 16 MB
  f16* Alo = (f16*)(ws + off); off += (size_t)MTOT * DIM * sizeof(f16);           // 16 MB
  f16* Whi = (f16*)(ws + off); off += (size_t)HID * DIM * sizeof(f16);            // 8 MB
  f16* Wlo = (f16*)(ws + off); off += (size_t)HID * DIM * sizeof(f16);            // 8 MB
  int* bpos = (int*)(ws + off); off += (size_t)BSZ * SEQ * sizeof(int);
  int* counts = (int*)(ws + off); off += 16 * sizeof(int);
  int* lengths = (int*)(ws + off); off += 16 * sizeof(int);
  off = (off + 255) & ~(size_t)255;
  float* tailpart = (float*)(ws + off);                                           // 256 KB

  split_all<<<NA_BLOCKS + NW_BLOCKS, 256, 0, stream>>>(hidden, Ahi, Alo,
                                                       W1, Whi, Wlo);
  gate_gemm<<<256, 512, 0, stream>>>(Ahi, Alo, Whi, Wlo, b1, W2, partial);
  boundary_scan<<<BSZ, 256, 0, stream>>>(partial, mask, noise, b2,
                                         bpos, counts, lengths, shortmask);
  pool_tail_partial<<<dim3(16, BSZ), 256, 0, stream>>>(hidden, bpos, counts,
                                                       lengths, tailpart, scalars);
  pool_seg<<<dim3(SEQ, BSZ), 256, 0, stream>>>(hidden, bpos, counts,
                                               tailpart, pooled);
}